// Round 3
// baseline (468.621 us; speedup 1.0000x reference)
//
#include <hip/hip_runtime.h>

typedef _Float16 half8 __attribute__((ext_vector_type(8)));
typedef _Float16 half4 __attribute__((ext_vector_type(4)));
typedef _Float16 half2t __attribute__((ext_vector_type(2)));
typedef float f32x4 __attribute__((ext_vector_type(4)));
typedef float f32x2 __attribute__((ext_vector_type(2)));

#define NHEAD 16
#define SEQ 512
#define DIM 128
#define HID 2048
#define SCACHE 8192
#define CAP 64
#define SCALE 0.08838834764831845f   // 1/sqrt(128)
#define NEG_INF (-__builtin_inff())
#define RECMAX 2048                  // per-block record slab (hits ~150, Poisson sigma ~12)

// ---------------------------------------------------------------------------
// Split-K tile GEMM: Cpart[kblk] = A[M,K] @ B[N,K]^T slice (f16 MFMA).
// 128x128 tiles, BK=64. Smooth outputs only (k/v, out-proj) — q must not.
// ---------------------------------------------------------------------------
__global__ __launch_bounds__(256) void gemm_xwT(const float* __restrict__ A,
                                                const float* __restrict__ B,
                                                float* __restrict__ Cpart,
                                                int K, int gridN, int kslices) {
  __shared__ __align__(16) _Float16 As[128][84];
  __shared__ __align__(16) _Float16 Bs[128][84];
  int b = blockIdx.x;
  int kblk = b % kslices;
  int nm = b / kslices;
  int nblk = nm % gridN, mblk = nm / gridN;
  int N = gridN * 128;
  int kchunk = K / kslices;
  int t = threadIdx.x;
  int lane = t & 63, wid = t >> 6;
  int wm = (wid >> 1) * 64, wn = (wid & 1) * 64;
  f32x4 acc[4][4] = {};
  const float* Ab = A + (size_t)mblk * 128 * K;
  const float* Bb = B + (size_t)nblk * 128 * K;
  int rowS = t >> 4, c4 = (t & 15) * 4;

  for (int k0 = kblk * kchunk; k0 < kblk * kchunk + kchunk; k0 += 64) {
#pragma unroll
    for (int i = 0; i < 8; ++i) {
      int row = rowS + 16 * i;
      float4 av = *(const float4*)(Ab + (size_t)row * K + k0 + c4);
      float4 bv = *(const float4*)(Bb + (size_t)row * K + k0 + c4);
      half4 ah = {(_Float16)av.x, (_Float16)av.y, (_Float16)av.z, (_Float16)av.w};
      half4 bh = {(_Float16)bv.x, (_Float16)bv.y, (_Float16)bv.z, (_Float16)bv.w};
      *(half4*)&As[row][c4] = ah;
      *(half4*)&Bs[row][c4] = bh;
    }
    __syncthreads();
#pragma unroll
    for (int ks = 0; ks < 2; ++ks) {
      int ko = ks * 32 + (lane >> 4) * 8;
      int rr = lane & 15;
      half8 af[4], bf[4];
#pragma unroll
      for (int i = 0; i < 4; ++i) af[i] = *(const half8*)&As[wm + i * 16 + rr][ko];
#pragma unroll
      for (int j = 0; j < 4; ++j) bf[j] = *(const half8*)&Bs[wn + j * 16 + rr][ko];
#pragma unroll
      for (int i = 0; i < 4; ++i)
#pragma unroll
        for (int j = 0; j < 4; ++j)
          acc[i][j] = __builtin_amdgcn_mfma_f32_16x16x32_f16(af[i], bf[j], acc[i][j], 0, 0, 0);
    }
    __syncthreads();
  }
  float* Cp = Cpart + (size_t)kblk * ((size_t)gridN * 128) * 512;
  int cR = (lane >> 4) * 4, cC = lane & 15;
#pragma unroll
  for (int i = 0; i < 4; ++i)
#pragma unroll
    for (int j = 0; j < 4; ++j) {
      int row = mblk * 128 + wm + i * 16 + cR;
      int col = nblk * 128 + wn + j * 16 + cC;
#pragma unroll
      for (int r = 0; r < 4; ++r)
        Cp[(size_t)(row + r) * N + col] = acc[i][j][r];
    }
}

// Deterministic split-K reduce.
__global__ __launch_bounds__(256) void reduce_k(const float* __restrict__ part,
                                                float* __restrict__ dst,
                                                int kslices, int ncol, int dstride) {
  size_t e = ((size_t)blockIdx.x * 256 + threadIdx.x) * 4;
  size_t slice = (size_t)512 * ncol;
  f32x4 s = *(const f32x4*)(part + e);
  for (int p = 1; p < kslices; ++p)
    s += *(const f32x4*)(part + (size_t)p * slice + e);
  size_t row = e / ncol;
  int col = (int)(e % ncol);
  *(f32x4*)(dst + row * dstride + col) = s;
}

// ---------------------------------------------------------------------------
// Streaming fp32 -> (f16 hi, f16 lo) split. Per-element arithmetic IDENTICAL
// to the former in-GEMM conversion (hi=(f16)x, lo=(f16)(x-(float)hi)) —
// q's bits depend on these exact values.
// ---------------------------------------------------------------------------
__global__ __launch_bounds__(256) void split_hilo(const float* __restrict__ src,
                                                  _Float16* __restrict__ hi,
                                                  _Float16* __restrict__ lo) {
  size_t e = ((size_t)blockIdx.x * 256 + threadIdx.x) * 4;
  f32x4 v = *(const f32x4*)(src + e);
  half4 h = {(_Float16)v[0], (_Float16)v[1], (_Float16)v[2], (_Float16)v[3]};
  half4 l = {(_Float16)(v[0] - (float)h[0]), (_Float16)(v[1] - (float)h[1]),
             (_Float16)(v[2] - (float)h[2]), (_Float16)(v[3] - (float)h[3])};
  *(half4*)(hi + e) = h;
  *(half4*)(lo + e) = l;
}

// ---------------------------------------------------------------------------
// q-third at fp32 accuracy via 3-term f16 split MFMA on PRE-SPLIT inputs.
// BIT-IDENTICAL chain per output (K 0..2048 step 32, order lo*hi, hi*lo,
// hi*hi, acc=0). 32x32 tiles -> 1024 blocks (4/CU, 16 waves/CU).
// Writes into qkv cols 0..2047 (stride 6144).
// ---------------------------------------------------------------------------
__global__ __launch_bounds__(256) void gemm_q_hi(const _Float16* __restrict__ Ahg,
                                                 const _Float16* __restrict__ Alg,
                                                 const _Float16* __restrict__ Bhg,
                                                 const _Float16* __restrict__ Blg,
                                                 float* __restrict__ C) {
  __shared__ __align__(16) _Float16 Ahs[32][72], Als[32][72];
  __shared__ __align__(16) _Float16 Bhs[32][72], Bls[32][72];
  int b = blockIdx.x;
  int nblk = b & 63, mblk = b >> 6;   // 64 n-tiles x 16 m-tiles
  int t = threadIdx.x, lane = t & 63, w = t >> 6;
  int wm = (w >> 1) * 16, wn = (w & 1) * 16;
  int quad = lane >> 4, rr = lane & 15;
  f32x4 acc = {};
  const _Float16* Ab0 = Ahg + (size_t)(mblk * 32) * 2048;
  const _Float16* Ab1 = Alg + (size_t)(mblk * 32) * 2048;
  const _Float16* Bb0 = Bhg + (size_t)(nblk * 32) * 2048;
  const _Float16* Bb1 = Blg + (size_t)(nblk * 32) * 2048;
  int srow = t >> 3, sc = (t & 7) * 8;

  for (int k0 = 0; k0 < 2048; k0 += 64) {
    size_t goff = (size_t)srow * 2048 + k0 + sc;
    *(uint4*)&Ahs[srow][sc] = *(const uint4*)(Ab0 + goff);
    *(uint4*)&Als[srow][sc] = *(const uint4*)(Ab1 + goff);
    *(uint4*)&Bhs[srow][sc] = *(const uint4*)(Bb0 + goff);
    *(uint4*)&Bls[srow][sc] = *(const uint4*)(Bb1 + goff);
    __syncthreads();
#pragma unroll
    for (int ks = 0; ks < 2; ++ks) {
      int ko = ks * 32 + quad * 8;
      half8 afh = *(const half8*)&Ahs[wm + rr][ko];
      half8 afl = *(const half8*)&Als[wm + rr][ko];
      half8 bfh = *(const half8*)&Bhs[wn + rr][ko];
      half8 bfl = *(const half8*)&Bls[wn + rr][ko];
      acc = __builtin_amdgcn_mfma_f32_16x16x32_f16(afl, bfh, acc, 0, 0, 0);
      acc = __builtin_amdgcn_mfma_f32_16x16x32_f16(afh, bfl, acc, 0, 0, 0);
      acc = __builtin_amdgcn_mfma_f32_16x16x32_f16(afh, bfh, acc, 0, 0, 0);
    }
    __syncthreads();
  }
  int row = mblk * 32 + wm + quad * 4;
  int col = nblk * 32 + wn + rr;
#pragma unroll
  for (int r = 0; r < 4; ++r)
    C[(size_t)(row + r) * (3 * HID) + col] = acc[r];
}

// ---------------------------------------------------------------------------
// k_cache: f16 normalized copy (filter) + double 1/||k|| (exact re-scoring).
// ---------------------------------------------------------------------------
__global__ __launch_bounds__(256) void cache_norm(const float* __restrict__ kc,
                                                  _Float16* __restrict__ kn16,
                                                  double* __restrict__ kninv) {
  int w = threadIdx.x >> 6, lane = threadIdx.x & 63;
  int row = blockIdx.x * 4 + w;
  f32x2 v = *(const f32x2*)(kc + (size_t)row * DIM + lane * 2);
  double s = (double)v[0] * v[0] + (double)v[1] * v[1];
#pragma unroll
  for (int off = 32; off; off >>= 1) s += __shfl_xor(s, off);
  float inv = rsqrtf((float)s);
  half2t o = {(_Float16)(v[0] * inv), (_Float16)(v[1] * inv)};
  *(half2t*)(kn16 + (size_t)row * DIM + lane * 2) = o;
  if (lane == 0) kninv[row] = 1.0 / sqrt(s);
}

// ---------------------------------------------------------------------------
// From qkv: per-head f16 q, k_local, normalized q. Wave per (h,s).
// ---------------------------------------------------------------------------
__global__ __launch_bounds__(256) void prep_local(const float* __restrict__ qkv,
                                                  _Float16* __restrict__ q16,
                                                  _Float16* __restrict__ k16,
                                                  _Float16* __restrict__ qn16) {
  int w = threadIdx.x >> 6, lane = threadIdx.x & 63;
  int rid = blockIdx.x * 4 + w;
  int h = rid >> 9, s = rid & 511;
  const float* qp = qkv + (size_t)s * (3 * HID) + h * DIM + lane * 2;
  f32x2 q = *(const f32x2*)qp;
  f32x2 k = *(const f32x2*)(qp + HID);
  float ss = q[0] * q[0] + q[1] * q[1];
#pragma unroll
  for (int off = 32; off; off >>= 1) ss += __shfl_xor(ss, off);
  float inv = rsqrtf(ss);
  half2t qh = {(_Float16)q[0], (_Float16)q[1]};
  half2t kh = {(_Float16)k[0], (_Float16)k[1]};
  half2t qnh = {(_Float16)(q[0] * inv), (_Float16)(q[1] * inv)};
  *(half2t*)(q16 + (size_t)rid * DIM + lane * 2) = qh;
  *(half2t*)(k16 + (size_t)rid * DIM + lane * 2) = kh;
  *(half2t*)(qn16 + (size_t)rid * DIM + lane * 2) = qnh;
}

// ---------------------------------------------------------------------------
// Candidate filter: sim = Qn @ Kn^T, f16 MFMA, threshold 0.249 (margin 1e-3).
// BARRIER-FREE qt loop: K-fragments live in registers (loaded once); Q
// A-fragments are loaded per-lane DIRECTLY from global (qn16 is 128 KB/head,
// reused by 64 consecutive blocks -> L1/L2-hot; all 4 waves issue identical
// addresses -> L1 broadcast). No Qs LDS, no per-qt __syncthreads, no forced
// vmcnt drains -> compiler pipelines qt+1 loads under qt MFMAs. LDS holds
// only the hit queue. (R2's LDS-staged version: 64KB redundant LDS reads/
// block/qt + bank conflicts + barrier-lockstep = ~50us of stall.)
// Hits: LDS queue -> per-block slab (plain stores; slab now aliases po,
// which is dead until attn_part — NOT the freshly-dirty gpart region whose
// L2 writeback storm cost R2 ~16us / +25MB WRITE_SIZE).
// ---------------------------------------------------------------------------
__global__ __launch_bounds__(256) void sim_cand(const _Float16* __restrict__ qn16,
                                                const _Float16* __restrict__ kn16,
                                                int* __restrict__ rec,
                                                int* __restrict__ reccnt) {
  __shared__ int ls_buf[RECMAX];
  __shared__ int ls_cnt;
  int b = blockIdx.x;
  int h = b >> 6, cblk = b & 63;   // consecutive blocks share a head -> Q locality
  int t = threadIdx.x, lane = t & 63, w = t >> 6;
  int quad = lane >> 4, rr = lane & 15;
  if (t == 0) ls_cnt = 0;
  __syncthreads();

  half8 bf[2][4];
  {
    const _Float16* kb = kn16 + ((size_t)(h * SCACHE + cblk * 128 + w * 32)) * DIM;
#pragma unroll
    for (int jn = 0; jn < 2; ++jn)
#pragma unroll
      for (int ks = 0; ks < 4; ++ks)
        bf[jn][ks] = *(const half8*)(kb + (size_t)(jn * 16 + rr) * DIM + ks * 32 + quad * 8);
  }

  const _Float16* qbase = qn16 + (size_t)h * SEQ * DIM + (size_t)rr * DIM + quad * 8;

  for (int qt = 0; qt < 8; ++qt) {
    const _Float16* qp = qbase + (size_t)(qt * 64) * DIM;
    f32x4 acc[4][2] = {};
#pragma unroll
    for (int ks = 0; ks < 4; ++ks) {
      half8 af[4];
#pragma unroll
      for (int i = 0; i < 4; ++i)
        af[i] = *(const half8*)(qp + (size_t)(i * 16) * DIM + ks * 32);
#pragma unroll
      for (int i = 0; i < 4; ++i)
#pragma unroll
        for (int j = 0; j < 2; ++j)
          acc[i][j] = __builtin_amdgcn_mfma_f32_16x16x32_f16(af[i], bf[j][ks], acc[i][j], 0, 0, 0);
    }
    int qrow_base = qt * 64 + (quad << 2);
    int key_base = cblk * 128 + w * 32 + rr;
#pragma unroll
    for (int i = 0; i < 4; ++i)
#pragma unroll
      for (int j = 0; j < 2; ++j)
#pragma unroll
        for (int r = 0; r < 4; ++r) {
          float v = acc[i][j][r];
          if (v > 0.249f) {
            int q = qrow_base + i * 16 + r;          // local q within head
            int p = atomicAdd(&ls_cnt, 1);           // LDS atomic only
            if (p < RECMAX) ls_buf[p] = (q << 13) | (key_base + j * 16);
          }
        }
  }
  __syncthreads();
  int total = ls_cnt;
  if (total > RECMAX) total = RECMAX;
  int* rp = rec + (size_t)b * RECMAX;
  for (int e = t; e < total; e += 256) rp[e] = ls_buf[e];  // plain coalesced stores
  if (t == 0) reccnt[b] = total;
}

// ---------------------------------------------------------------------------
// Scatter per-block record slabs into cnt/cidx. One block per head; the 64
// slabs of a head are split across the 4 waves (16 each). Only LDS atomics —
// rows of a head are owned by exactly this block.
// ---------------------------------------------------------------------------
__global__ __launch_bounds__(256) void cand_merge(const int* __restrict__ rec,
                                                  const int* __restrict__ reccnt,
                                                  int* __restrict__ cnt,
                                                  int* __restrict__ cidx) {
  __shared__ int lc[512];
  int h = blockIdx.x;
  int t = threadIdx.x, w = t >> 6, lane = t & 63;
  for (int i = t; i < 512; i += 256) lc[i] = 0;
  __syncthreads();
  for (int s8 = 0; s8 < 16; ++s8) {
    int cblk = s8 * 4 + w;               // cache-block index (0..63)
    int bA = h * 64 + cblk;              // phase-A block id (h-major mapping)
    int n = reccnt[bA];
    const int* rp = rec + (size_t)bA * RECMAX;
    for (int e = lane; e < n; e += 64) {
      int rv = rp[e];
      int q = rv >> 13, key = rv & 8191;
      int pos = atomicAdd(&lc[q], 1);
      if (pos < CAP) cidx[((size_t)h * 512 + q) * CAP + pos] = key;
    }
  }
  __syncthreads();
  for (int i = t; i < 512; i += 256) cnt[h * 512 + i] = lc[i];
}

// ---------------------------------------------------------------------------
// Candidate-parallel exact re-score + top-16 membership (double precision).
// ---------------------------------------------------------------------------
__global__ __launch_bounds__(256) void select_topk(const int* __restrict__ cnt,
                                                   const int* __restrict__ cidx,
                                                   const float* __restrict__ qkv,
                                                   const float* __restrict__ kcache,
                                                   const double* __restrict__ kninv,
                                                   int* __restrict__ sel_idx,
                                                   float* __restrict__ sel_score) {
  int w = threadIdx.x >> 6, lane = threadIdx.x & 63;
  int rowid = blockIdx.x * 4 + w;
  int h = rowid >> 9, s = rowid & 511;
  const float* qp = qkv + (size_t)s * (3 * HID) + h * DIM;

  f32x2 qv2 = *(const f32x2*)(qp + lane * 2);
  double qs = (double)qv2[0] * qv2[0] + (double)qv2[1] * qv2[1];
#pragma unroll
  for (int off = 32; off; off >>= 1) qs += __shfl_xor(qs, off);
  double thr = 0.25 * sqrt(qs);

  int n = min(cnt[rowid], CAP);
  int idx = 0x7fffffff;
  double r = -1e300, d = 0.0;
  if (lane < n) {
    idx = cidx[rowid * CAP + lane];
    const float* kp = kcache + ((size_t)(h * SCACHE + idx)) * DIM;
    double d0 = 0.0, d1 = 0.0;
#pragma unroll
    for (int j = 0; j < DIM; j += 8) {
      f32x4 ka = *(const f32x4*)(kp + j);
      f32x4 kb = *(const f32x4*)(kp + j + 4);
      f32x4 qa = *(const f32x4*)(qp + j);
      f32x4 qb = *(const f32x4*)(qp + j + 4);
      d0 = fma((double)qa[0], (double)ka[0], d0);
      d1 = fma((double)qa[1], (double)ka[1], d1);
      d0 = fma((double)qa[2], (double)ka[2], d0);
      d1 = fma((double)qa[3], (double)ka[3], d1);
      d0 = fma((double)qb[0], (double)kb[0], d0);
      d1 = fma((double)qb[1], (double)kb[1], d1);
      d0 = fma((double)qb[2], (double)kb[2], d0);
      d1 = fma((double)qb[3], (double)kb[3], d1);
    }
    d = d0 + d1;
    r = d * kninv[h * SCACHE + idx];
  }

  int rank = 0;
  for (int j = 0; j < n; ++j) {
    double rj = __shfl(r, j);
    int ij = __shfl(idx, j);
    if (rj > r || (rj == r && ij < idx)) ++rank;
  }
  bool sel = (lane < n) && (rank < 16) && (r > thr);
  unsigned long long m = __ballot(sel);
  int nsel = __popcll(m);
  if (sel) {
    int pos = __popcll(m & ((1ull << lane) - 1));
    sel_idx[rowid * 16 + pos] = idx;
    sel_score[rowid * 16 + pos] = (float)(d * (double)SCALE);
  }
  if (lane >= nsel && lane < 16) {
    sel_idx[rowid * 16 + lane] = 0;
    sel_score[rowid * 16 + lane] = NEG_INF;
  }
}

// ---------------------------------------------------------------------------
// Flash-style local attention, stage 1.
// ---------------------------------------------------------------------------
__global__ __launch_bounds__(256) void attn_part(const float* __restrict__ qkv,
                                                 const _Float16* __restrict__ q16,
                                                 const _Float16* __restrict__ k16,
                                                 const float* __restrict__ bias,
                                                 float* __restrict__ part_m,
                                                 float* __restrict__ part_l,
                                                 float* __restrict__ part_o) {
  __shared__ __align__(16) _Float16 Vs[128][136];  // V^T: [dim][key]
  __shared__ __align__(16) _Float16 Ps[16][136];   // P:   [q][key]
  __shared__ float mred[16][4], lred[16][4];

  int pb = blockIdx.x;
  int tt = pb % 80, h = pb / 80;
  int qb, cb;
  if (tt < 8)       { qb = tt;                cb = 0; }
  else if (tt < 24) { int u = tt - 8;  qb = 8 + (u >> 1); cb = u & 1; }
  else if (tt < 48) { int u = tt - 24; int q3 = u / 3; qb = 16 + q3; cb = u - q3 * 3; }
  else              { int u = tt - 48; qb = 24 + (u >> 2); cb = u & 3; }
  int q0 = qb * 16, kc0 = cb * 128;

  int t = threadIdx.x, lane = t & 63, w = t >> 6;
  int quad = lane >> 4, col = lane & 15;

  const float* vbase = qkv + 2 * HID + h * DIM;
#pragma unroll
  for (int i = 0; i < 16; ++i) {
    int idx = t + 256 * i;
    int key = idx & 127, dg = idx >> 7;
    f32x4 vv = *(const f32x4*)(vbase + (size_t)(kc0 + key) * (3 * HID) + dg * 4);
#pragma unroll
    for (int e = 0; e < 4; ++e) Vs[dg * 4 + e][key] = (_Float16)vv[e];
  }

  const _Float16* qbp = q16 + ((size_t)(h * SEQ + q0)) * DIM;
  half8 af[4];
#pragma unroll
  for (int ks = 0; ks < 4; ++ks)
    af[ks] = *(const half8*)(qbp + (size_t)col * DIM + ks * 32 + quad * 8);

  f32x4 acc[2] = {};
#pragma unroll
  for (int jn = 0; jn < 2; ++jn) {
    const _Float16* kp = k16 + ((size_t)(h * SEQ + kc0 + w * 32 + jn * 16 + col)) * DIM;
#pragma unroll
    for (int ks = 0; ks < 4; ++ks) {
      half8 bf = *(const half8*)(kp + ks * 32 + quad * 8);
      acc[jn] = __builtin_amdgcn_mfma_f32_16x16x32_f16(af[ks], bf, acc[jn], 0, 0, 0);
    }
  }
  float s[2][4];
#pragma unroll
  for (int jn = 0; jn < 2; ++jn) {
    int keyg = kc0 + w * 32 + jn * 16 + col;
#pragma unroll
    for (int r = 0; r < 4; ++r) {
      int qrow = q0 + quad * 4 + r;
      float sv = NEG_INF;
      if (keyg <= qrow)
        sv = acc[jn][r] * SCALE + bias[((size_t)h * SEQ + qrow) * SEQ + keyg];
      s[jn][r] = sv;
    }
  }

  float mw[4];
#pragma unroll
  for (int r = 0; r < 4; ++r) {
    float m = fmaxf(s[0][r], s[1][r]);
#pragma unroll
    for (int off = 1; off < 16; off <<= 1) m = fmaxf(m, __shfl_xor(m, off));
    mw[r] = m;
  }
  if (col == 0)
#pragma unroll
    for (int r = 0; r < 4; ++r) mred[quad * 4 + r][w] = mw[r];
  __syncthreads();

  float M[4];
#pragma unroll
  for (int r = 0; r < 4; ++r) {
    int row = quad * 4 + r;
    float m = fmaxf(fmaxf(mred[row][0], mred[row][1]),
                    fmaxf(mred[row][2], mred[row][3]));
    M[r] = m;
    float p0 = __expf(s[0][r] - m);
    float p1 = __expf(s[1][r] - m);
    Ps[row][w * 32 + col] = (_Float16)p0;
    Ps[row][w * 32 + 16 + col] = (_Float16)p1;
    float l = p0 + p1;
#pragma unroll
    for (int off = 1; off < 16; off <<= 1) l += __shfl_xor(l, off);
    if (col == 0) lred[row][w] = l;
  }
  if (w == 0 && col == 0)
#pragma unroll
    for (int r = 0; r < 4; ++r) part_m[pb * 16 + quad * 4 + r] = M[r];
  __syncthreads();

  f32x4 o[2] = {};
#pragma unroll
  for (int jn = 0; jn < 2; ++jn) {
#pragma unroll
    for (int ks = 0; ks < 4; ++ks) {
      half8 a = *(const half8*)&Ps[col][ks * 32 + quad * 8];
      half8 bv = *(const half8*)&Vs[w * 32 + jn * 16 + col][ks * 32 + quad * 8];
      o[jn] = __builtin_amdgcn_mfma_f32_16x16x32_f16(a, bv, o[jn], 0, 0, 0);
    }
  }
#pragma unroll
  for (int jn = 0; jn < 2; ++jn)
#pragma unroll
    for (int r = 0; r < 4; ++r)
      part_o[((size_t)pb * 16 + quad * 4 + r) * 128 + w * 32 + jn * 16 + col] = o[jn][r];
  if (t < 16)
    part_l[pb * 16 + t] = lred[t][0] + lred[t][1] + lred[t][2] + lred[t][3];
}

// ---------------------------------------------------------------------------
// Flash merge: wave per (h,q) row.
// ---------------------------------------------------------------------------
__global__ __launch_bounds__(256) void attn_merge(const float* __restrict__ part_m,
                                                  const float* __restrict__ part_l,
                                                  const float* __restrict__ part_o,
                                                  const int* __restrict__ sel_idx,
                                                  const float* __restrict__ sel_score,
                                                  const float* __restrict__ vcache,
                                                  float* __restrict__ ctx) {
  int w = threadIdx.x >> 6, lane = threadIdx.x & 63;
  int row = blockIdx.x * 4 + w;
  int h = row >> 9, q = row & 511;
  int qb = q >> 4, r = q & 15;
  int base = (qb < 8) ? qb
           : (qb < 16) ? 8 + 2 * (qb - 8)
           : (qb < 24) ? 24 + 3 * (qb - 16)
                       : 48 + 4 * (qb - 24);
  int ncb = (qb >> 3) + 1;
  int pb0 = h * 80 + base;

  float scv[16], mc = NEG_INF;
#pragma unroll
  for (int j = 0; j < 16; ++j) {
    scv[j] = sel_score[row * 16 + j];
    mc = fmaxf(mc, scv[j]);
  }
  float mi[4];
  float M = mc;
  for (int i = 0; i < ncb; ++i) {
    mi[i] = part_m[(pb0 + i) * 16 + r];
    M = fmaxf(M, mi[i]);
  }
  f32x2 O = {0.f, 0.f};
  float L = 0.f;
  for (int i = 0; i < ncb; ++i) {
    float sc = __expf(mi[i] - M);
    f32x2 ov = *(const f32x2*)(part_o + ((size_t)(pb0 + i) * 16 + r) * 128 + lane * 2);
    O += ov * sc;
    L += part_l[(pb0 + i) * 16 + r] * sc;
  }
#pragma unroll
  for (int j = 0; j < 16; ++j) {
    if (scv[j] > NEG_INF) {
      float wv = __expf(scv[j] - M);
      int idx = sel_idx[row * 16 + j];
      f32x2 v = *(const f32x2*)(vcache + ((size_t)(h * SCACHE + idx)) * DIM + lane * 2);
      O += v * wv;
      L += wv;
    }
  }
  f32x2 res = O * (1.f / L);
  *(f32x2*)(ctx + (size_t)q * HID + h * DIM + lane * 2) = res;
}

// ---------------------------------------------------------------------------
extern "C" void kernel_launch(void* const* d_in, const int* in_sizes, int n_in,
                              void* d_out, int out_size, void* d_ws, size_t ws_size,
                              hipStream_t stream) {
  const float* hidden = (const float*)d_in[0];
  const float* Wqkv   = (const float*)d_in[1];
  const float* Wout   = (const float*)d_in[2];
  const float* kcache = (const float*)d_in[3];
  const float* vcache = (const float*)d_in[4];
  const float* bias   = (const float*)d_in[5];

  char* ws = (char*)d_ws;
  size_t off = 0;
  float*    qkv   = (float*)(ws + off);    off += (size_t)SEQ * 3 * HID * 4;
  _Float16* q16   = (_Float16*)(ws + off); off += (size_t)NHEAD * SEQ * DIM * 2;
  _Float16* k16   = (_Float16*)(ws + off); off += (size_t)NHEAD * SEQ * DIM * 2;
  _Float16* qn16  = (_Float16*)(ws + off); off += (size_t)NHEAD * SEQ * DIM * 2;
  _Float16* kn16  = (_Float16*)(ws + off); off += (size_t)NHEAD * SCACHE * DIM * 2;
  double*   kninv = (double*)(ws + off);   off += (size_t)NHEAD * SCACHE * 8;
  int*      ccnt  = (int*)(ws + off);      off += (size_t)NHEAD * SEQ * 4;
  int*      cidx  = (int*)(ws + off);      off += (size_t)NHEAD * SEQ * CAP * 4;
  int*      selidx  = (int*)(ws + off);    off += (size_t)NHEAD * SEQ * 16 * 4;
  float*    selsc   = (float*)(ws + off);  off += (size_t)NHEAD * SEQ * 16 * 4;
  float*    ctx   = (float*)(ws + off);    off += (size_t)SEQ * HID * 4;
  float*    pm    = (float*)(ws + off);    off += (size_t)1280 * 16 * 4;
  float*    pl    = (float*)(ws + off);    off += (size_t)1280 * 16 * 4;
  float*    po    = (float*)(ws + off);    off += (size_t)1280 * 16 * 128 * 4;
  // po region (10.5 MB) is dead until attn_part: sim_cand's record slabs
  // (8 MB + 4 KB) alias it. Prior-iteration po dirt is ~14 dispatches stale
  // (evicted), unlike gpart which is dirty from split_hilo 3 dispatches ago
  // — that aliasing cost R2 a ~25 MB L2-writeback storm inside sim_cand.
  int*      rec    = (int*)po;
  int*      reccnt = rec + (size_t)1024 * RECMAX;
  // 32 MB union region, three disjoint lifetimes on the serial stream:
  //  (1) kv split-K partials    (kv gemm -> kv reduce)
  //  (2) q hi/lo f16 buffers    (split_hilo -> gemm_q_hi)   [20 MB]
  //  (3) out-proj partials      (out gemm -> out reduce)
  float*    gpart = (float*)(ws + off);
  _Float16* Ahg = (_Float16*)gpart;                       // 512*2048 f16 = 2 MB
  _Float16* Alg = Ahg + (size_t)SEQ * HID;
  _Float16* Bhg = Alg + (size_t)SEQ * HID;                // 2048*2048 f16 = 8 MB
  _Float16* Blg = Bhg + (size_t)HID * HID;

  cache_norm<<<dim3(NHEAD * SCACHE / 4), dim3(256), 0, stream>>>(kcache, kn16, kninv);
  // k/v thirds: split-K=4, 512 blocks; reduce into qkv cols 2048+ (stride 6144)
  gemm_xwT<<<dim3(4 * 32 * 4), dim3(256), 0, stream>>>(hidden, Wqkv + (size_t)2048 * 2048,
                                                       gpart, 2048, 32, 4);
  reduce_k<<<dim3(SEQ * 4096 / 1024), dim3(256), 0, stream>>>(gpart, qkv + 2048, 4, 4096,
                                                              3 * HID);
  // q third: pre-split hi/lo, then bit-identical 3-term chain, 1024 blocks
  split_hilo<<<dim3(SEQ * HID / 1024), dim3(256), 0, stream>>>(hidden, Ahg, Alg);
  split_hilo<<<dim3(HID * HID / 1024), dim3(256), 0, stream>>>(Wqkv, Bhg, Blg);
  gemm_q_hi<<<dim3(1024), dim3(256), 0, stream>>>(Ahg, Alg, Bhg, Blg, qkv);
  prep_local<<<dim3(NHEAD * SEQ / 4), dim3(256), 0, stream>>>(qkv, q16, k16, qn16);
  sim_cand<<<dim3(NHEAD * 64), dim3(256), 0, stream>>>(qn16, kn16, rec, reccnt);
  cand_merge<<<dim3(NHEAD), dim3(256), 0, stream>>>(rec, reccnt, ccnt, cidx);
  select_topk<<<dim3(NHEAD * SEQ / 4), dim3(256), 0, stream>>>(ccnt, cidx, qkv, kcache,
                                                               kninv, selidx, selsc);
  attn_part<<<dim3(16 * 80), dim3(256), 0, stream>>>(qkv, q16, k16, bias, pm, pl, po);
  attn_merge<<<dim3(NHEAD * SEQ / 4), dim3(256), 0, stream>>>(pm, pl, po, selidx, selsc,
                                                              vcache, ctx);
  // out-proj: split-K=8, 512 blocks; reduce into d_out
  gemm_xwT<<<dim3(4 * 16 * 8), dim3(256), 0, stream>>>(ctx, Wout, gpart, 2048, 16, 8);
  reduce_k<<<dim3(SEQ * 2048 / 1024), dim3(256), 0, stream>>>(gpart, (float*)d_out, 8, 2048,
                                                              2048);
}

// Round 4
// 463.944 us; speedup vs baseline: 1.0101x; 1.0101x over previous
//
#include <hip/hip_runtime.h>

typedef _Float16 half8 __attribute__((ext_vector_type(8)));
typedef _Float16 half4 __attribute__((ext_vector_type(4)));
typedef _Float16 half2t __attribute__((ext_vector_type(2)));
typedef float f32x4 __attribute__((ext_vector_type(4)));
typedef float f32x2 __attribute__((ext_vector_type(2)));

#define NHEAD 16
#define SEQ 512
#define DIM 128
#define HID 2048
#define SCACHE 8192
#define CAP 64
#define SCALE 0.08838834764831845f   // 1/sqrt(128)
#define NEG_INF (-__builtin_inff())
#define RECMAX 512                   // per-block slab (mean hits ~40, 12.8x headroom)

// ---------------------------------------------------------------------------
// Split-K tile GEMM: Cpart[kblk] = A[M,K] @ B[N,K]^T slice (f16 MFMA).
// 128x128 tiles, BK=64. Smooth outputs only (k/v, out-proj) — q must not.
// ---------------------------------------------------------------------------
__global__ __launch_bounds__(256) void gemm_xwT(const float* __restrict__ A,
                                                const float* __restrict__ B,
                                                float* __restrict__ Cpart,
                                                int K, int gridN, int kslices) {
  __shared__ __align__(16) _Float16 As[128][84];
  __shared__ __align__(16) _Float16 Bs[128][84];
  int b = blockIdx.x;
  int kblk = b % kslices;
  int nm = b / kslices;
  int nblk = nm % gridN, mblk = nm / gridN;
  int N = gridN * 128;
  int kchunk = K / kslices;
  int t = threadIdx.x;
  int lane = t & 63, wid = t >> 6;
  int wm = (wid >> 1) * 64, wn = (wid & 1) * 64;
  f32x4 acc[4][4] = {};
  const float* Ab = A + (size_t)mblk * 128 * K;
  const float* Bb = B + (size_t)nblk * 128 * K;
  int rowS = t >> 4, c4 = (t & 15) * 4;

  for (int k0 = kblk * kchunk; k0 < kblk * kchunk + kchunk; k0 += 64) {
#pragma unroll
    for (int i = 0; i < 8; ++i) {
      int row = rowS + 16 * i;
      float4 av = *(const float4*)(Ab + (size_t)row * K + k0 + c4);
      float4 bv = *(const float4*)(Bb + (size_t)row * K + k0 + c4);
      half4 ah = {(_Float16)av.x, (_Float16)av.y, (_Float16)av.z, (_Float16)av.w};
      half4 bh = {(_Float16)bv.x, (_Float16)bv.y, (_Float16)bv.z, (_Float16)bv.w};
      *(half4*)&As[row][c4] = ah;
      *(half4*)&Bs[row][c4] = bh;
    }
    __syncthreads();
#pragma unroll
    for (int ks = 0; ks < 2; ++ks) {
      int ko = ks * 32 + (lane >> 4) * 8;
      int rr = lane & 15;
      half8 af[4], bf[4];
#pragma unroll
      for (int i = 0; i < 4; ++i) af[i] = *(const half8*)&As[wm + i * 16 + rr][ko];
#pragma unroll
      for (int j = 0; j < 4; ++j) bf[j] = *(const half8*)&Bs[wn + j * 16 + rr][ko];
#pragma unroll
      for (int i = 0; i < 4; ++i)
#pragma unroll
        for (int j = 0; j < 4; ++j)
          acc[i][j] = __builtin_amdgcn_mfma_f32_16x16x32_f16(af[i], bf[j], acc[i][j], 0, 0, 0);
    }
    __syncthreads();
  }
  float* Cp = Cpart + (size_t)kblk * ((size_t)gridN * 128) * 512;
  int cR = (lane >> 4) * 4, cC = lane & 15;
#pragma unroll
  for (int i = 0; i < 4; ++i)
#pragma unroll
    for (int j = 0; j < 4; ++j) {
      int row = mblk * 128 + wm + i * 16 + cR;
      int col = nblk * 128 + wn + j * 16 + cC;
#pragma unroll
      for (int r = 0; r < 4; ++r)
        Cp[(size_t)(row + r) * N + col] = acc[i][j][r];
    }
}

// Deterministic split-K reduce.
__global__ __launch_bounds__(256) void reduce_k(const float* __restrict__ part,
                                                float* __restrict__ dst,
                                                int kslices, int ncol, int dstride) {
  size_t e = ((size_t)blockIdx.x * 256 + threadIdx.x) * 4;
  size_t slice = (size_t)512 * ncol;
  f32x4 s = *(const f32x4*)(part + e);
  for (int p = 1; p < kslices; ++p)
    s += *(const f32x4*)(part + (size_t)p * slice + e);
  size_t row = e / ncol;
  int col = (int)(e % ncol);
  *(f32x4*)(dst + row * dstride + col) = s;
}

// ---------------------------------------------------------------------------
// Streaming fp32 -> (f16 hi, f16 lo) split. Per-element arithmetic IDENTICAL
// to the former in-GEMM conversion (hi=(f16)x, lo=(f16)(x-(float)hi)) —
// q's bits depend on these exact values.
// ---------------------------------------------------------------------------
__global__ __launch_bounds__(256) void split_hilo(const float* __restrict__ src,
                                                  _Float16* __restrict__ hi,
                                                  _Float16* __restrict__ lo) {
  size_t e = ((size_t)blockIdx.x * 256 + threadIdx.x) * 4;
  f32x4 v = *(const f32x4*)(src + e);
  half4 h = {(_Float16)v[0], (_Float16)v[1], (_Float16)v[2], (_Float16)v[3]};
  half4 l = {(_Float16)(v[0] - (float)h[0]), (_Float16)(v[1] - (float)h[1]),
             (_Float16)(v[2] - (float)h[2]), (_Float16)(v[3] - (float)h[3])};
  *(half4*)(hi + e) = h;
  *(half4*)(lo + e) = l;
}

// ---------------------------------------------------------------------------
// q-third at fp32 accuracy via 3-term f16 split MFMA on PRE-SPLIT inputs.
// BIT-IDENTICAL chain per output (K 0..2048 step 32, order lo*hi, hi*lo,
// hi*hi, acc=0). 32x32 tiles -> 1024 blocks (4/CU, 16 waves/CU).
// Writes into qkv cols 0..2047 (stride 6144).
// ---------------------------------------------------------------------------
__global__ __launch_bounds__(256) void gemm_q_hi(const _Float16* __restrict__ Ahg,
                                                 const _Float16* __restrict__ Alg,
                                                 const _Float16* __restrict__ Bhg,
                                                 const _Float16* __restrict__ Blg,
                                                 float* __restrict__ C) {
  __shared__ __align__(16) _Float16 Ahs[32][72], Als[32][72];
  __shared__ __align__(16) _Float16 Bhs[32][72], Bls[32][72];
  int b = blockIdx.x;
  int nblk = b & 63, mblk = b >> 6;   // 64 n-tiles x 16 m-tiles
  int t = threadIdx.x, lane = t & 63, w = t >> 6;
  int wm = (w >> 1) * 16, wn = (w & 1) * 16;
  int quad = lane >> 4, rr = lane & 15;
  f32x4 acc = {};
  const _Float16* Ab0 = Ahg + (size_t)(mblk * 32) * 2048;
  const _Float16* Ab1 = Alg + (size_t)(mblk * 32) * 2048;
  const _Float16* Bb0 = Bhg + (size_t)(nblk * 32) * 2048;
  const _Float16* Bb1 = Blg + (size_t)(nblk * 32) * 2048;
  int srow = t >> 3, sc = (t & 7) * 8;

  for (int k0 = 0; k0 < 2048; k0 += 64) {
    size_t goff = (size_t)srow * 2048 + k0 + sc;
    *(uint4*)&Ahs[srow][sc] = *(const uint4*)(Ab0 + goff);
    *(uint4*)&Als[srow][sc] = *(const uint4*)(Ab1 + goff);
    *(uint4*)&Bhs[srow][sc] = *(const uint4*)(Bb0 + goff);
    *(uint4*)&Bls[srow][sc] = *(const uint4*)(Bb1 + goff);
    __syncthreads();
#pragma unroll
    for (int ks = 0; ks < 2; ++ks) {
      int ko = ks * 32 + quad * 8;
      half8 afh = *(const half8*)&Ahs[wm + rr][ko];
      half8 afl = *(const half8*)&Als[wm + rr][ko];
      half8 bfh = *(const half8*)&Bhs[wn + rr][ko];
      half8 bfl = *(const half8*)&Bls[wn + rr][ko];
      acc = __builtin_amdgcn_mfma_f32_16x16x32_f16(afl, bfh, acc, 0, 0, 0);
      acc = __builtin_amdgcn_mfma_f32_16x16x32_f16(afh, bfl, acc, 0, 0, 0);
      acc = __builtin_amdgcn_mfma_f32_16x16x32_f16(afh, bfh, acc, 0, 0, 0);
    }
    __syncthreads();
  }
  int row = mblk * 32 + wm + quad * 4;
  int col = nblk * 32 + wn + rr;
#pragma unroll
  for (int r = 0; r < 4; ++r)
    C[(size_t)(row + r) * (3 * HID) + col] = acc[r];
}

// ---------------------------------------------------------------------------
// k_cache: f16 normalized copy (filter) + double 1/||k|| (exact re-scoring).
// ---------------------------------------------------------------------------
__global__ __launch_bounds__(256) void cache_norm(const float* __restrict__ kc,
                                                  _Float16* __restrict__ kn16,
                                                  double* __restrict__ kninv) {
  int w = threadIdx.x >> 6, lane = threadIdx.x & 63;
  int row = blockIdx.x * 4 + w;
  f32x2 v = *(const f32x2*)(kc + (size_t)row * DIM + lane * 2);
  double s = (double)v[0] * v[0] + (double)v[1] * v[1];
#pragma unroll
  for (int off = 32; off; off >>= 1) s += __shfl_xor(s, off);
  float inv = rsqrtf((float)s);
  half2t o = {(_Float16)(v[0] * inv), (_Float16)(v[1] * inv)};
  *(half2t*)(kn16 + (size_t)row * DIM + lane * 2) = o;
  if (lane == 0) kninv[row] = 1.0 / sqrt(s);
}

// ---------------------------------------------------------------------------
// From qkv: per-head f16 q, k_local, normalized q. Wave per (h,s).
// ---------------------------------------------------------------------------
__global__ __launch_bounds__(256) void prep_local(const float* __restrict__ qkv,
                                                  _Float16* __restrict__ q16,
                                                  _Float16* __restrict__ k16,
                                                  _Float16* __restrict__ qn16) {
  int w = threadIdx.x >> 6, lane = threadIdx.x & 63;
  int rid = blockIdx.x * 4 + w;
  int h = rid >> 9, s = rid & 511;
  const float* qp = qkv + (size_t)s * (3 * HID) + h * DIM + lane * 2;
  f32x2 q = *(const f32x2*)qp;
  f32x2 k = *(const f32x2*)(qp + HID);
  float ss = q[0] * q[0] + q[1] * q[1];
#pragma unroll
  for (int off = 32; off; off >>= 1) ss += __shfl_xor(ss, off);
  float inv = rsqrtf(ss);
  half2t qh = {(_Float16)q[0], (_Float16)q[1]};
  half2t kh = {(_Float16)k[0], (_Float16)k[1]};
  half2t qnh = {(_Float16)(q[0] * inv), (_Float16)(q[1] * inv)};
  *(half2t*)(q16 + (size_t)rid * DIM + lane * 2) = qh;
  *(half2t*)(k16 + (size_t)rid * DIM + lane * 2) = kh;
  *(half2t*)(qn16 + (size_t)rid * DIM + lane * 2) = qnh;
}

// ---------------------------------------------------------------------------
// Candidate filter: sim = Qn @ Kn^T, f16 MFMA, threshold 0.249 (margin 1e-3).
// SINGLE-PHASE GEMM structure (R3 was latency-serialized: 16 global A-loads
// feeding MFMAs per qt-iter, 8 serial iters, 382 GB/s effective = 64us).
// Now: block = 128q x 128keys, K=128 in ONE shot. A-tile staged to LDS once
// (XOR-swizzled 16B chunks -> ds_read_b128 at bank floor), B-frags in regs,
// ONE barrier, then 64 dense MFMAs/wave. 16 independent loads/thread before
// the barrier -> full MLP. Same MFMA shape + ks-order -> bit-identical sims
// -> identical candidate sets.
// XCD-aware mapping: the 4 sibling blocks (mq=0..3) sharing a kn16 tile land
// on the same XCD so B is HBM-fetched once per tile.
// Hits: LDS queue -> per-block slab (aliases po; dead until attn_part).
// ---------------------------------------------------------------------------
__global__ __launch_bounds__(256) void sim_cand(const _Float16* __restrict__ qn16,
                                                const _Float16* __restrict__ kn16,
                                                int* __restrict__ rec,
                                                int* __restrict__ reccnt) {
  __shared__ __align__(16) _Float16 As[128 * 128];  // 32 KB, swizzled chunks
  __shared__ int ls_buf[RECMAX];
  __shared__ int ls_cnt;
  int b = blockIdx.x;
  int xcd = b & 7, slot = b >> 3;
  int mq = slot & 3;                  // q-quarter within head
  int p = (slot >> 2) * 8 + xcd;      // 0..1023 = h*64 + nblk
  int h = p >> 6, nblk = p & 63;
  int t = threadIdx.x, lane = t & 63, w = t >> 6;
  int quad = lane >> 4, rr = lane & 15;
  if (t == 0) ls_cnt = 0;

  // B-fragments: wave w owns keys nblk*128 + w*32 .. +31
  half8 bf[2][4];
  {
    const _Float16* kb = kn16 + ((size_t)(h * SCACHE + nblk * 128 + w * 32)) * DIM;
#pragma unroll
    for (int jn = 0; jn < 2; ++jn)
#pragma unroll
      for (int ks = 0; ks < 4; ++ks)
        bf[jn][ks] = *(const half8*)(kb + (size_t)(jn * 16 + rr) * DIM + ks * 32 + quad * 8);
  }

  // Stage A-tile (128 q-rows x 128 K): 8 coalesced 16B loads/thread, then
  // ds_write at chunk (c ^ (row&7)) — read side undoes the XOR.
  {
    const _Float16* qA = qn16 + ((size_t)(h * SEQ + mq * 128)) * DIM;
    uint4 sreg[8];
#pragma unroll
    for (int i = 0; i < 8; ++i) {
      int f = t + 256 * i;
      sreg[i] = *(const uint4*)(qA + (size_t)(f >> 4) * DIM + (f & 15) * 8);
    }
#pragma unroll
    for (int i = 0; i < 8; ++i) {
      int f = t + 256 * i;
      int row = f >> 4, c = f & 15;
      *(uint4*)&As[row * DIM + ((c ^ (row & 7)) * 8)] = sreg[i];
    }
  }
  __syncthreads();

  f32x4 acc[8][2] = {};
#pragma unroll
  for (int i = 0; i < 8; ++i) {
    int R = i * 16 + rr;
    half8 af[4];
#pragma unroll
    for (int ks = 0; ks < 4; ++ks)
      af[ks] = *(const half8*)&As[R * DIM + (((ks * 4 + quad) ^ (rr & 7)) * 8)];
#pragma unroll
    for (int jn = 0; jn < 2; ++jn)
#pragma unroll
      for (int ks = 0; ks < 4; ++ks)
        acc[i][jn] = __builtin_amdgcn_mfma_f32_16x16x32_f16(af[ks], bf[jn][ks], acc[i][jn], 0, 0, 0);
  }

#pragma unroll
  for (int i = 0; i < 8; ++i)
#pragma unroll
    for (int jn = 0; jn < 2; ++jn)
#pragma unroll
      for (int r = 0; r < 4; ++r) {
        float v = acc[i][jn][r];
        if (v > 0.249f) {
          int q = mq * 128 + i * 16 + quad * 4 + r;        // head-local q row
          int key = nblk * 128 + w * 32 + jn * 16 + rr;
          int pq = atomicAdd(&ls_cnt, 1);                  // LDS atomic only
          if (pq < RECMAX) ls_buf[pq] = (q << 13) | key;
        }
      }
  __syncthreads();
  int total = ls_cnt;
  if (total > RECMAX) total = RECMAX;
  int* rp = rec + (size_t)b * RECMAX;
  for (int e = t; e < total; e += 256) rp[e] = ls_buf[e];  // plain coalesced stores
  if (t == 0) reccnt[b] = total;
}

// ---------------------------------------------------------------------------
// Scatter per-block record slabs into cnt/cidx. One block per head; the 256
// slabs of a head split across the 4 waves. Only LDS atomics — rows of a
// head are owned by exactly this block.
// ---------------------------------------------------------------------------
__global__ __launch_bounds__(256) void cand_merge(const int* __restrict__ rec,
                                                  const int* __restrict__ reccnt,
                                                  int* __restrict__ cnt,
                                                  int* __restrict__ cidx) {
  __shared__ int lc[512];
  int h = blockIdx.x;
  int t = threadIdx.x, w = t >> 6, lane = t & 63;
  for (int i = t; i < 512; i += 256) lc[i] = 0;
  __syncthreads();
  for (int u = w; u < 256; u += 4) {
    int s = u >> 2, mq = u & 3;
    int p = h * 64 + s;                                   // h*64 + nblk
    int bA = (p & 7) + 8 * (((p >> 3) << 2) + mq);        // inverse XCD map
    int n = reccnt[bA];
    const int* rp = rec + (size_t)bA * RECMAX;
    for (int e = lane; e < n; e += 64) {
      int rv = rp[e];
      int q = rv >> 13, key = rv & 8191;
      int pos = atomicAdd(&lc[q], 1);
      if (pos < CAP) cidx[((size_t)h * 512 + q) * CAP + pos] = key;
    }
  }
  __syncthreads();
  for (int i = t; i < 512; i += 256) cnt[h * 512 + i] = lc[i];
}

// ---------------------------------------------------------------------------
// Candidate-parallel exact re-score + top-16 membership (double precision).
// ---------------------------------------------------------------------------
__global__ __launch_bounds__(256) void select_topk(const int* __restrict__ cnt,
                                                   const int* __restrict__ cidx,
                                                   const float* __restrict__ qkv,
                                                   const float* __restrict__ kcache,
                                                   const double* __restrict__ kninv,
                                                   int* __restrict__ sel_idx,
                                                   float* __restrict__ sel_score) {
  int w = threadIdx.x >> 6, lane = threadIdx.x & 63;
  int rowid = blockIdx.x * 4 + w;
  int h = rowid >> 9, s = rowid & 511;
  const float* qp = qkv + (size_t)s * (3 * HID) + h * DIM;

  f32x2 qv2 = *(const f32x2*)(qp + lane * 2);
  double qs = (double)qv2[0] * qv2[0] + (double)qv2[1] * qv2[1];
#pragma unroll
  for (int off = 32; off; off >>= 1) qs += __shfl_xor(qs, off);
  double thr = 0.25 * sqrt(qs);

  int n = min(cnt[rowid], CAP);
  int idx = 0x7fffffff;
  double r = -1e300, d = 0.0;
  if (lane < n) {
    idx = cidx[rowid * CAP + lane];
    const float* kp = kcache + ((size_t)(h * SCACHE + idx)) * DIM;
    double d0 = 0.0, d1 = 0.0;
#pragma unroll
    for (int j = 0; j < DIM; j += 8) {
      f32x4 ka = *(const f32x4*)(kp + j);
      f32x4 kb = *(const f32x4*)(kp + j + 4);
      f32x4 qa = *(const f32x4*)(qp + j);
      f32x4 qb = *(const f32x4*)(qp + j + 4);
      d0 = fma((double)qa[0], (double)ka[0], d0);
      d1 = fma((double)qa[1], (double)ka[1], d1);
      d0 = fma((double)qa[2], (double)ka[2], d0);
      d1 = fma((double)qa[3], (double)ka[3], d1);
      d0 = fma((double)qb[0], (double)kb[0], d0);
      d1 = fma((double)qb[1], (double)kb[1], d1);
      d0 = fma((double)qb[2], (double)kb[2], d0);
      d1 = fma((double)qb[3], (double)kb[3], d1);
    }
    d = d0 + d1;
    r = d * kninv[h * SCACHE + idx];
  }

  int rank = 0;
  for (int j = 0; j < n; ++j) {
    double rj = __shfl(r, j);
    int ij = __shfl(idx, j);
    if (rj > r || (rj == r && ij < idx)) ++rank;
  }
  bool sel = (lane < n) && (rank < 16) && (r > thr);
  unsigned long long m = __ballot(sel);
  int nsel = __popcll(m);
  if (sel) {
    int pos = __popcll(m & ((1ull << lane) - 1));
    sel_idx[rowid * 16 + pos] = idx;
    sel_score[rowid * 16 + pos] = (float)(d * (double)SCALE);
  }
  if (lane >= nsel && lane < 16) {
    sel_idx[rowid * 16 + lane] = 0;
    sel_score[rowid * 16 + lane] = NEG_INF;
  }
}

// ---------------------------------------------------------------------------
// Flash-style local attention, stage 1.
// ---------------------------------------------------------------------------
__global__ __launch_bounds__(256) void attn_part(const float* __restrict__ qkv,
                                                 const _Float16* __restrict__ q16,
                                                 const _Float16* __restrict__ k16,
                                                 const float* __restrict__ bias,
                                                 float* __restrict__ part_m,
                                                 float* __restrict__ part_l,
                                                 float* __restrict__ part_o) {
  __shared__ __align__(16) _Float16 Vs[128][136];  // V^T: [dim][key]
  __shared__ __align__(16) _Float16 Ps[16][136];   // P:   [q][key]
  __shared__ float mred[16][4], lred[16][4];

  int pb = blockIdx.x;
  int tt = pb % 80, h = pb / 80;
  int qb, cb;
  if (tt < 8)       { qb = tt;                cb = 0; }
  else if (tt < 24) { int u = tt - 8;  qb = 8 + (u >> 1); cb = u & 1; }
  else if (tt < 48) { int u = tt - 24; int q3 = u / 3; qb = 16 + q3; cb = u - q3 * 3; }
  else              { int u = tt - 48; qb = 24 + (u >> 2); cb = u & 3; }
  int q0 = qb * 16, kc0 = cb * 128;

  int t = threadIdx.x, lane = t & 63, w = t >> 6;
  int quad = lane >> 4, col = lane & 15;

  const float* vbase = qkv + 2 * HID + h * DIM;
#pragma unroll
  for (int i = 0; i < 16; ++i) {
    int idx = t + 256 * i;
    int key = idx & 127, dg = idx >> 7;
    f32x4 vv = *(const f32x4*)(vbase + (size_t)(kc0 + key) * (3 * HID) + dg * 4);
#pragma unroll
    for (int e = 0; e < 4; ++e) Vs[dg * 4 + e][key] = (_Float16)vv[e];
  }

  const _Float16* qbp = q16 + ((size_t)(h * SEQ + q0)) * DIM;
  half8 af[4];
#pragma unroll
  for (int ks = 0; ks < 4; ++ks)
    af[ks] = *(const half8*)(qbp + (size_t)col * DIM + ks * 32 + quad * 8);

  f32x4 acc[2] = {};
#pragma unroll
  for (int jn = 0; jn < 2; ++jn) {
    const _Float16* kp = k16 + ((size_t)(h * SEQ + kc0 + w * 32 + jn * 16 + col)) * DIM;
#pragma unroll
    for (int ks = 0; ks < 4; ++ks) {
      half8 bf = *(const half8*)(kp + ks * 32 + quad * 8);
      acc[jn] = __builtin_amdgcn_mfma_f32_16x16x32_f16(af[ks], bf, acc[jn], 0, 0, 0);
    }
  }
  float s[2][4];
#pragma unroll
  for (int jn = 0; jn < 2; ++jn) {
    int keyg = kc0 + w * 32 + jn * 16 + col;
#pragma unroll
    for (int r = 0; r < 4; ++r) {
      int qrow = q0 + quad * 4 + r;
      float sv = NEG_INF;
      if (keyg <= qrow)
        sv = acc[jn][r] * SCALE + bias[((size_t)h * SEQ + qrow) * SEQ + keyg];
      s[jn][r] = sv;
    }
  }

  float mw[4];
#pragma unroll
  for (int r = 0; r < 4; ++r) {
    float m = fmaxf(s[0][r], s[1][r]);
#pragma unroll
    for (int off = 1; off < 16; off <<= 1) m = fmaxf(m, __shfl_xor(m, off));
    mw[r] = m;
  }
  if (col == 0)
#pragma unroll
    for (int r = 0; r < 4; ++r) mred[quad * 4 + r][w] = mw[r];
  __syncthreads();

  float M[4];
#pragma unroll
  for (int r = 0; r < 4; ++r) {
    int row = quad * 4 + r;
    float m = fmaxf(fmaxf(mred[row][0], mred[row][1]),
                    fmaxf(mred[row][2], mred[row][3]));
    M[r] = m;
    float p0 = __expf(s[0][r] - m);
    float p1 = __expf(s[1][r] - m);
    Ps[row][w * 32 + col] = (_Float16)p0;
    Ps[row][w * 32 + 16 + col] = (_Float16)p1;
    float l = p0 + p1;
#pragma unroll
    for (int off = 1; off < 16; off <<= 1) l += __shfl_xor(l, off);
    if (col == 0) lred[row][w] = l;
  }
  if (w == 0 && col == 0)
#pragma unroll
    for (int r = 0; r < 4; ++r) part_m[pb * 16 + quad * 4 + r] = M[r];
  __syncthreads();

  f32x4 o[2] = {};
#pragma unroll
  for (int jn = 0; jn < 2; ++jn) {
#pragma unroll
    for (int ks = 0; ks < 4; ++ks) {
      half8 a = *(const half8*)&Ps[col][ks * 32 + quad * 8];
      half8 bv = *(const half8*)&Vs[w * 32 + jn * 16 + col][ks * 32 + quad * 8];
      o[jn] = __builtin_amdgcn_mfma_f32_16x16x32_f16(a, bv, o[jn], 0, 0, 0);
    }
  }
#pragma unroll
  for (int jn = 0; jn < 2; ++jn)
#pragma unroll
    for (int r = 0; r < 4; ++r)
      part_o[((size_t)pb * 16 + quad * 4 + r) * 128 + w * 32 + jn * 16 + col] = o[jn][r];
  if (t < 16)
    part_l[pb * 16 + t] = lred[t][0] + lred[t][1] + lred[t][2] + lred[t][3];
}

// ---------------------------------------------------------------------------
// Flash merge: wave per (h,q) row.
// ---------------------------------------------------------------------------
__global__ __launch_bounds__(256) void attn_merge(const float* __restrict__ part_m,
                                                  const float* __restrict__ part_l,
                                                  const float* __restrict__ part_o,
                                                  const int* __restrict__ sel_idx,
                                                  const float* __restrict__ sel_score,
                                                  const float* __restrict__ vcache,
                                                  float* __restrict__ ctx) {
  int w = threadIdx.x >> 6, lane = threadIdx.x & 63;
  int row = blockIdx.x * 4 + w;
  int h = row >> 9, q = row & 511;
  int qb = q >> 4, r = q & 15;
  int base = (qb < 8) ? qb
           : (qb < 16) ? 8 + 2 * (qb - 8)
           : (qb < 24) ? 24 + 3 * (qb - 16)
                       : 48 + 4 * (qb - 24);
  int ncb = (qb >> 3) + 1;
  int pb0 = h * 80 + base;

  float scv[16], mc = NEG_INF;
#pragma unroll
  for (int j = 0; j < 16; ++j) {
    scv[j] = sel_score[row * 16 + j];
    mc = fmaxf(mc, scv[j]);
  }
  float mi[4];
  float M = mc;
  for (int i = 0; i < ncb; ++i) {
    mi[i] = part_m[(pb0 + i) * 16 + r];
    M = fmaxf(M, mi[i]);
  }
  f32x2 O = {0.f, 0.f};
  float L = 0.f;
  for (int i = 0; i < ncb; ++i) {
    float sc = __expf(mi[i] - M);
    f32x2 ov = *(const f32x2*)(part_o + ((size_t)(pb0 + i) * 16 + r) * 128 + lane * 2);
    O += ov * sc;
    L += part_l[(pb0 + i) * 16 + r] * sc;
  }
#pragma unroll
  for (int j = 0; j < 16; ++j) {
    if (scv[j] > NEG_INF) {
      float wv = __expf(scv[j] - M);
      int idx = sel_idx[row * 16 + j];
      f32x2 v = *(const f32x2*)(vcache + ((size_t)(h * SCACHE + idx)) * DIM + lane * 2);
      O += v * wv;
      L += wv;
    }
  }
  f32x2 res = O * (1.f / L);
  *(f32x2*)(ctx + (size_t)q * HID + h * DIM + lane * 2) = res;
}

// ---------------------------------------------------------------------------
extern "C" void kernel_launch(void* const* d_in, const int* in_sizes, int n_in,
                              void* d_out, int out_size, void* d_ws, size_t ws_size,
                              hipStream_t stream) {
  const float* hidden = (const float*)d_in[0];
  const float* Wqkv   = (const float*)d_in[1];
  const float* Wout   = (const float*)d_in[2];
  const float* kcache = (const float*)d_in[3];
  const float* vcache = (const float*)d_in[4];
  const float* bias   = (const float*)d_in[5];

  char* ws = (char*)d_ws;
  size_t off = 0;
  float*    qkv   = (float*)(ws + off);    off += (size_t)SEQ * 3 * HID * 4;
  _Float16* q16   = (_Float16*)(ws + off); off += (size_t)NHEAD * SEQ * DIM * 2;
  _Float16* k16   = (_Float16*)(ws + off); off += (size_t)NHEAD * SEQ * DIM * 2;
  _Float16* qn16  = (_Float16*)(ws + off); off += (size_t)NHEAD * SEQ * DIM * 2;
  _Float16* kn16  = (_Float16*)(ws + off); off += (size_t)NHEAD * SCACHE * DIM * 2;
  double*   kninv = (double*)(ws + off);   off += (size_t)NHEAD * SCACHE * 8;
  int*      ccnt  = (int*)(ws + off);      off += (size_t)NHEAD * SEQ * 4;
  int*      cidx  = (int*)(ws + off);      off += (size_t)NHEAD * SEQ * CAP * 4;
  int*      selidx  = (int*)(ws + off);    off += (size_t)NHEAD * SEQ * 16 * 4;
  float*    selsc   = (float*)(ws + off);  off += (size_t)NHEAD * SEQ * 16 * 4;
  float*    ctx   = (float*)(ws + off);    off += (size_t)SEQ * HID * 4;
  float*    pm    = (float*)(ws + off);    off += (size_t)1280 * 16 * 4;
  float*    pl    = (float*)(ws + off);    off += (size_t)1280 * 16 * 4;
  float*    po    = (float*)(ws + off);    off += (size_t)1280 * 16 * 128 * 4;
  // po region (10.5 MB) is dead until attn_part: sim_cand's record slabs
  // (8 MB + 16 KB) alias it. Prior-iteration po dirt is many dispatches
  // stale (evicted) — unlike gpart, which R2 showed costs a writeback storm.
  int*      rec    = (int*)po;
  int*      reccnt = rec + (size_t)4096 * RECMAX;
  // 32 MB union region, three disjoint lifetimes on the serial stream:
  //  (1) kv split-K partials    (kv gemm -> kv reduce)
  //  (2) q hi/lo f16 buffers    (split_hilo -> gemm_q_hi)   [20 MB]
  //  (3) out-proj partials      (out gemm -> out reduce)
  float*    gpart = (float*)(ws + off);
  _Float16* Ahg = (_Float16*)gpart;                       // 512*2048 f16 = 2 MB
  _Float16* Alg = Ahg + (size_t)SEQ * HID;
  _Float16* Bhg = Alg + (size_t)SEQ * HID;                // 2048*2048 f16 = 8 MB
  _Float16* Blg = Bhg + (size_t)HID * HID;

  cache_norm<<<dim3(NHEAD * SCACHE / 4), dim3(256), 0, stream>>>(kcache, kn16, kninv);
  // k/v thirds: split-K=4, 512 blocks; reduce into qkv cols 2048+ (stride 6144)
  gemm_xwT<<<dim3(4 * 32 * 4), dim3(256), 0, stream>>>(hidden, Wqkv + (size_t)2048 * 2048,
                                                       gpart, 2048, 32, 4);
  reduce_k<<<dim3(SEQ * 4096 / 1024), dim3(256), 0, stream>>>(gpart, qkv + 2048, 4, 4096,
                                                              3 * HID);
  // q third: pre-split hi/lo, then bit-identical 3-term chain, 1024 blocks
  split_hilo<<<dim3(SEQ * HID / 1024), dim3(256), 0, stream>>>(hidden, Ahg, Alg);
  split_hilo<<<dim3(HID * HID / 1024), dim3(256), 0, stream>>>(Wqkv, Bhg, Blg);
  gemm_q_hi<<<dim3(1024), dim3(256), 0, stream>>>(Ahg, Alg, Bhg, Blg, qkv);
  prep_local<<<dim3(NHEAD * SEQ / 4), dim3(256), 0, stream>>>(qkv, q16, k16, qn16);
  sim_cand<<<dim3(4096), dim3(256), 0, stream>>>(qn16, kn16, rec, reccnt);
  cand_merge<<<dim3(NHEAD), dim3(256), 0, stream>>>(rec, reccnt, ccnt, cidx);
  select_topk<<<dim3(NHEAD * SEQ / 4), dim3(256), 0, stream>>>(ccnt, cidx, qkv, kcache,
                                                               kninv, selidx, selsc);
  attn_part<<<dim3(16 * 80), dim3(256), 0, stream>>>(qkv, q16, k16, bias, pm, pl, po);
  attn_merge<<<dim3(NHEAD * SEQ / 4), dim3(256), 0, stream>>>(pm, pl, po, selidx, selsc,
                                                              vcache, ctx);
  // out-proj: split-K=8, 512 blocks; reduce into d_out
  gemm_xwT<<<dim3(4 * 16 * 8), dim3(256), 0, stream>>>(ctx, Wout, gpart, 2048, 16, 8);
  reduce_k<<<dim3(SEQ * 2048 / 1024), dim3(256), 0, stream>>>(gpart, (float*)d_out, 8, 2048,
                                                              2048);
}

// Round 5
// 419.193 us; speedup vs baseline: 1.1179x; 1.1068x over previous
//
#include <hip/hip_runtime.h>

typedef _Float16 half8 __attribute__((ext_vector_type(8)));
typedef _Float16 half4 __attribute__((ext_vector_type(4)));
typedef _Float16 half2t __attribute__((ext_vector_type(2)));
typedef float f32x4 __attribute__((ext_vector_type(4)));
typedef float f32x2 __attribute__((ext_vector_type(2)));

#define NHEAD 16
#define SEQ 512
#define DIM 128
#define HID 2048
#define SCACHE 8192
#define CAP 64
#define SCALE 0.08838834764831845f   // 1/sqrt(128)
#define NEG_INF (-__builtin_inff())
#define RECMAX 512                   // per-block slab (mean hits ~40, 12.8x headroom)

// ---------------------------------------------------------------------------
// Split-K tile GEMM: Cpart[kblk] = A[M,K] @ B[N,K]^T slice (f16 MFMA).
// 128x128 tiles, BK=64. Smooth outputs only (k/v, out-proj) — q must not.
// ---------------------------------------------------------------------------
__global__ __launch_bounds__(256) void gemm_xwT(const float* __restrict__ A,
                                                const float* __restrict__ B,
                                                float* __restrict__ Cpart,
                                                int K, int gridN, int kslices) {
  __shared__ __align__(16) _Float16 As[128][84];
  __shared__ __align__(16) _Float16 Bs[128][84];
  int b = blockIdx.x;
  int kblk = b % kslices;
  int nm = b / kslices;
  int nblk = nm % gridN, mblk = nm / gridN;
  int N = gridN * 128;
  int kchunk = K / kslices;
  int t = threadIdx.x;
  int lane = t & 63, wid = t >> 6;
  int wm = (wid >> 1) * 64, wn = (wid & 1) * 64;
  f32x4 acc[4][4] = {};
  const float* Ab = A + (size_t)mblk * 128 * K;
  const float* Bb = B + (size_t)nblk * 128 * K;
  int rowS = t >> 4, c4 = (t & 15) * 4;

  for (int k0 = kblk * kchunk; k0 < kblk * kchunk + kchunk; k0 += 64) {
#pragma unroll
    for (int i = 0; i < 8; ++i) {
      int row = rowS + 16 * i;
      float4 av = *(const float4*)(Ab + (size_t)row * K + k0 + c4);
      float4 bv = *(const float4*)(Bb + (size_t)row * K + k0 + c4);
      half4 ah = {(_Float16)av.x, (_Float16)av.y, (_Float16)av.z, (_Float16)av.w};
      half4 bh = {(_Float16)bv.x, (_Float16)bv.y, (_Float16)bv.z, (_Float16)bv.w};
      *(half4*)&As[row][c4] = ah;
      *(half4*)&Bs[row][c4] = bh;
    }
    __syncthreads();
#pragma unroll
    for (int ks = 0; ks < 2; ++ks) {
      int ko = ks * 32 + (lane >> 4) * 8;
      int rr = lane & 15;
      half8 af[4], bf[4];
#pragma unroll
      for (int i = 0; i < 4; ++i) af[i] = *(const half8*)&As[wm + i * 16 + rr][ko];
#pragma unroll
      for (int j = 0; j < 4; ++j) bf[j] = *(const half8*)&Bs[wn + j * 16 + rr][ko];
#pragma unroll
      for (int i = 0; i < 4; ++i)
#pragma unroll
        for (int j = 0; j < 4; ++j)
          acc[i][j] = __builtin_amdgcn_mfma_f32_16x16x32_f16(af[i], bf[j], acc[i][j], 0, 0, 0);
    }
    __syncthreads();
  }
  float* Cp = Cpart + (size_t)kblk * ((size_t)gridN * 128) * 512;
  int cR = (lane >> 4) * 4, cC = lane & 15;
#pragma unroll
  for (int i = 0; i < 4; ++i)
#pragma unroll
    for (int j = 0; j < 4; ++j) {
      int row = mblk * 128 + wm + i * 16 + cR;
      int col = nblk * 128 + wn + j * 16 + cC;
#pragma unroll
      for (int r = 0; r < 4; ++r)
        Cp[(size_t)(row + r) * N + col] = acc[i][j][r];
    }
}

// Deterministic split-K reduce.
__global__ __launch_bounds__(256) void reduce_k(const float* __restrict__ part,
                                                float* __restrict__ dst,
                                                int kslices, int ncol, int dstride) {
  size_t e = ((size_t)blockIdx.x * 256 + threadIdx.x) * 4;
  size_t slice = (size_t)512 * ncol;
  f32x4 s = *(const f32x4*)(part + e);
  for (int p = 1; p < kslices; ++p)
    s += *(const f32x4*)(part + (size_t)p * slice + e);
  size_t row = e / ncol;
  int col = (int)(e % ncol);
  *(f32x4*)(dst + row * dstride + col) = s;
}

// ---------------------------------------------------------------------------
// Streaming fp32 -> (f16 hi, f16 lo) split. Per-element arithmetic IDENTICAL
// to the former in-GEMM conversion (hi=(f16)x, lo=(f16)(x-(float)hi)) —
// q's bits depend on these exact values.
// ---------------------------------------------------------------------------
__global__ __launch_bounds__(256) void split_hilo(const float* __restrict__ src,
                                                  _Float16* __restrict__ hi,
                                                  _Float16* __restrict__ lo) {
  size_t e = ((size_t)blockIdx.x * 256 + threadIdx.x) * 4;
  f32x4 v = *(const f32x4*)(src + e);
  half4 h = {(_Float16)v[0], (_Float16)v[1], (_Float16)v[2], (_Float16)v[3]};
  half4 l = {(_Float16)(v[0] - (float)h[0]), (_Float16)(v[1] - (float)h[1]),
             (_Float16)(v[2] - (float)h[2]), (_Float16)(v[3] - (float)h[3])};
  *(half4*)(hi + e) = h;
  *(half4*)(lo + e) = l;
}

// ---------------------------------------------------------------------------
// q-third at fp32 accuracy via 3-term f16 split MFMA on PRE-SPLIT inputs.
// BIT-IDENTICAL chain per output (K 0..2048 step 32, order lo*hi, hi*lo,
// hi*hi, acc=0). 32x32 tiles -> 1024 blocks (4/CU, 16 waves/CU).
// Writes into qkv cols 0..2047 (stride 6144).
// ---------------------------------------------------------------------------
__global__ __launch_bounds__(256) void gemm_q_hi(const _Float16* __restrict__ Ahg,
                                                 const _Float16* __restrict__ Alg,
                                                 const _Float16* __restrict__ Bhg,
                                                 const _Float16* __restrict__ Blg,
                                                 float* __restrict__ C) {
  __shared__ __align__(16) _Float16 Ahs[32][72], Als[32][72];
  __shared__ __align__(16) _Float16 Bhs[32][72], Bls[32][72];
  int b = blockIdx.x;
  int nblk = b & 63, mblk = b >> 6;   // 64 n-tiles x 16 m-tiles
  int t = threadIdx.x, lane = t & 63, w = t >> 6;
  int wm = (w >> 1) * 16, wn = (w & 1) * 16;
  int quad = lane >> 4, rr = lane & 15;
  f32x4 acc = {};
  const _Float16* Ab0 = Ahg + (size_t)(mblk * 32) * 2048;
  const _Float16* Ab1 = Alg + (size_t)(mblk * 32) * 2048;
  const _Float16* Bb0 = Bhg + (size_t)(nblk * 32) * 2048;
  const _Float16* Bb1 = Blg + (size_t)(nblk * 32) * 2048;
  int srow = t >> 3, sc = (t & 7) * 8;

  for (int k0 = 0; k0 < 2048; k0 += 64) {
    size_t goff = (size_t)srow * 2048 + k0 + sc;
    *(uint4*)&Ahs[srow][sc] = *(const uint4*)(Ab0 + goff);
    *(uint4*)&Als[srow][sc] = *(const uint4*)(Ab1 + goff);
    *(uint4*)&Bhs[srow][sc] = *(const uint4*)(Bb0 + goff);
    *(uint4*)&Bls[srow][sc] = *(const uint4*)(Bb1 + goff);
    __syncthreads();
#pragma unroll
    for (int ks = 0; ks < 2; ++ks) {
      int ko = ks * 32 + quad * 8;
      half8 afh = *(const half8*)&Ahs[wm + rr][ko];
      half8 afl = *(const half8*)&Als[wm + rr][ko];
      half8 bfh = *(const half8*)&Bhs[wn + rr][ko];
      half8 bfl = *(const half8*)&Bls[wn + rr][ko];
      acc = __builtin_amdgcn_mfma_f32_16x16x32_f16(afl, bfh, acc, 0, 0, 0);
      acc = __builtin_amdgcn_mfma_f32_16x16x32_f16(afh, bfl, acc, 0, 0, 0);
      acc = __builtin_amdgcn_mfma_f32_16x16x32_f16(afh, bfh, acc, 0, 0, 0);
    }
    __syncthreads();
  }
  int row = mblk * 32 + wm + quad * 4;
  int col = nblk * 32 + wn + rr;
#pragma unroll
  for (int r = 0; r < 4; ++r)
    C[(size_t)(row + r) * (3 * HID) + col] = acc[r];
}

// ---------------------------------------------------------------------------
// k_cache: f16 normalized copy (filter) + double 1/||k|| (exact re-scoring).
// ---------------------------------------------------------------------------
__global__ __launch_bounds__(256) void cache_norm(const float* __restrict__ kc,
                                                  _Float16* __restrict__ kn16,
                                                  double* __restrict__ kninv) {
  int w = threadIdx.x >> 6, lane = threadIdx.x & 63;
  int row = blockIdx.x * 4 + w;
  f32x2 v = *(const f32x2*)(kc + (size_t)row * DIM + lane * 2);
  double s = (double)v[0] * v[0] + (double)v[1] * v[1];
#pragma unroll
  for (int off = 32; off; off >>= 1) s += __shfl_xor(s, off);
  float inv = rsqrtf((float)s);
  half2t o = {(_Float16)(v[0] * inv), (_Float16)(v[1] * inv)};
  *(half2t*)(kn16 + (size_t)row * DIM + lane * 2) = o;
  if (lane == 0) kninv[row] = 1.0 / sqrt(s);
}

// ---------------------------------------------------------------------------
// From qkv: per-head f16 q, k_local, normalized q. Wave per (h,s).
// ---------------------------------------------------------------------------
__global__ __launch_bounds__(256) void prep_local(const float* __restrict__ qkv,
                                                  _Float16* __restrict__ q16,
                                                  _Float16* __restrict__ k16,
                                                  _Float16* __restrict__ qn16) {
  int w = threadIdx.x >> 6, lane = threadIdx.x & 63;
  int rid = blockIdx.x * 4 + w;
  int h = rid >> 9, s = rid & 511;
  const float* qp = qkv + (size_t)s * (3 * HID) + h * DIM + lane * 2;
  f32x2 q = *(const f32x2*)qp;
  f32x2 k = *(const f32x2*)(qp + HID);
  float ss = q[0] * q[0] + q[1] * q[1];
#pragma unroll
  for (int off = 32; off; off >>= 1) ss += __shfl_xor(ss, off);
  float inv = rsqrtf(ss);
  half2t qh = {(_Float16)q[0], (_Float16)q[1]};
  half2t kh = {(_Float16)k[0], (_Float16)k[1]};
  half2t qnh = {(_Float16)(q[0] * inv), (_Float16)(q[1] * inv)};
  *(half2t*)(q16 + (size_t)rid * DIM + lane * 2) = qh;
  *(half2t*)(k16 + (size_t)rid * DIM + lane * 2) = kh;
  *(half2t*)(qn16 + (size_t)rid * DIM + lane * 2) = qnh;
}

// ---------------------------------------------------------------------------
// Candidate filter: sim = Qn @ Kn^T, f16 MFMA, threshold 0.249 (margin 1e-3).
// Single-phase GEMM: block = 128q x 128keys, K=128 in one shot. A-tile in
// LDS (XOR-swizzled), B-frags in regs, one barrier, 64 dense MFMAs/wave.
// Same MFMA shape + ks-order -> bit-identical sims -> identical candidates.
// XCD-aware mapping: 4 sibling blocks (mq) share a kn16 tile per XCD-L2.
// Hits: LDS queue -> per-block slab (aliases po; dead until attn_part).
// ---------------------------------------------------------------------------
__global__ __launch_bounds__(256) void sim_cand(const _Float16* __restrict__ qn16,
                                                const _Float16* __restrict__ kn16,
                                                int* __restrict__ rec,
                                                int* __restrict__ reccnt) {
  __shared__ __align__(16) _Float16 As[128 * 128];  // 32 KB, swizzled chunks
  __shared__ int ls_buf[RECMAX];
  __shared__ int ls_cnt;
  int b = blockIdx.x;
  int xcd = b & 7, slot = b >> 3;
  int mq = slot & 3;                  // q-quarter within head
  int p = (slot >> 2) * 8 + xcd;      // 0..1023 = h*64 + nblk
  int h = p >> 6, nblk = p & 63;
  int t = threadIdx.x, lane = t & 63, w = t >> 6;
  int quad = lane >> 4, rr = lane & 15;
  if (t == 0) ls_cnt = 0;

  // B-fragments: wave w owns keys nblk*128 + w*32 .. +31
  half8 bf[2][4];
  {
    const _Float16* kb = kn16 + ((size_t)(h * SCACHE + nblk * 128 + w * 32)) * DIM;
#pragma unroll
    for (int jn = 0; jn < 2; ++jn)
#pragma unroll
      for (int ks = 0; ks < 4; ++ks)
        bf[jn][ks] = *(const half8*)(kb + (size_t)(jn * 16 + rr) * DIM + ks * 32 + quad * 8);
  }

  // Stage A-tile (128 q-rows x 128 K): 8 coalesced 16B loads/thread, then
  // ds_write at chunk (c ^ (row&7)) — read side undoes the XOR.
  {
    const _Float16* qA = qn16 + ((size_t)(h * SEQ + mq * 128)) * DIM;
    uint4 sreg[8];
#pragma unroll
    for (int i = 0; i < 8; ++i) {
      int f = t + 256 * i;
      sreg[i] = *(const uint4*)(qA + (size_t)(f >> 4) * DIM + (f & 15) * 8);
    }
#pragma unroll
    for (int i = 0; i < 8; ++i) {
      int f = t + 256 * i;
      int row = f >> 4, c = f & 15;
      *(uint4*)&As[row * DIM + ((c ^ (row & 7)) * 8)] = sreg[i];
    }
  }
  __syncthreads();

  f32x4 acc[8][2] = {};
#pragma unroll
  for (int i = 0; i < 8; ++i) {
    int R = i * 16 + rr;
    half8 af[4];
#pragma unroll
    for (int ks = 0; ks < 4; ++ks)
      af[ks] = *(const half8*)&As[R * DIM + (((ks * 4 + quad) ^ (rr & 7)) * 8)];
#pragma unroll
    for (int jn = 0; jn < 2; ++jn)
#pragma unroll
      for (int ks = 0; ks < 4; ++ks)
        acc[i][jn] = __builtin_amdgcn_mfma_f32_16x16x32_f16(af[ks], bf[jn][ks], acc[i][jn], 0, 0, 0);
  }

#pragma unroll
  for (int i = 0; i < 8; ++i)
#pragma unroll
    for (int jn = 0; jn < 2; ++jn)
#pragma unroll
      for (int r = 0; r < 4; ++r) {
        float v = acc[i][jn][r];
        if (v > 0.249f) {
          int q = mq * 128 + i * 16 + quad * 4 + r;        // head-local q row
          int key = nblk * 128 + w * 32 + jn * 16 + rr;
          int pq = atomicAdd(&ls_cnt, 1);                  // LDS atomic only
          if (pq < RECMAX) ls_buf[pq] = (q << 13) | key;
        }
      }
  __syncthreads();
  int total = ls_cnt;
  if (total > RECMAX) total = RECMAX;
  int* rp = rec + (size_t)b * RECMAX;
  for (int e = t; e < total; e += 256) rp[e] = ls_buf[e];  // plain coalesced stores
  if (t == 0) reccnt[b] = total;
}

// ---------------------------------------------------------------------------
// Scatter per-block record slabs into cnt/cidx.
// R4 lesson: 16 blocks x 64 serialized {cnt-load -> record-load -> scatter}
// iterations = 55.9us of pure exposed latency (occ 0.63%, all pipes <1%).
// Now: 64 blocks, one per (h, mq) — record q field encodes mq, so row
// ownership stays disjoint (LDS counters only). FLAT COOPERATIVE DRAIN:
// gather the 64 slab counts, prefix-sum in LDS, then all 256 threads walk
// the flat record space with INDEPENDENT loads (2-way unrolled -> 2 global
// loads in flight) — ~5 latency rounds instead of 128.
// ---------------------------------------------------------------------------
__global__ __launch_bounds__(256) void cand_merge(const int* __restrict__ rec,
                                                  const int* __restrict__ reccnt,
                                                  int* __restrict__ cnt,
                                                  int* __restrict__ cidx) {
  __shared__ int lc[128];
  __shared__ int pfx[65];
  __shared__ int bAs[64];
  int blk = blockIdx.x;              // 0..63
  int h = blk >> 2, mq = blk & 3;
  int t = threadIdx.x;
  if (t < 128) lc[t] = 0;
  if (t < 64) {
    int p = h * 64 + t;                               // h*64 + nblk
    int bA = (p & 7) + 8 * (((p >> 3) << 2) + mq);    // inverse XCD map
    bAs[t] = bA;
    pfx[t + 1] = reccnt[bA];
  }
  if (t == 0) pfx[0] = 0;
  __syncthreads();
  if (t == 0) {
    int s = 0;
    for (int i = 1; i <= 64; ++i) { s += pfx[i]; pfx[i] = s; }
  }
  __syncthreads();
  int T = pfx[64];

  for (int e0 = t; e0 < T; e0 += 512) {
    int e1 = e0 + 256;
    // two independent binary searches (LDS) + two independent global loads
    int lo0 = 0, hi0 = 64;
#pragma unroll
    for (int it = 0; it < 6; ++it) {
      int mid = (lo0 + hi0) >> 1;
      if (pfx[mid] <= e0) lo0 = mid; else hi0 = mid;
    }
    int lo1 = 0;
    if (e1 < T) {
      int hi1 = 64;
#pragma unroll
      for (int it = 0; it < 6; ++it) {
        int mid = (lo1 + hi1) >> 1;
        if (pfx[mid] <= e1) lo1 = mid; else hi1 = mid;
      }
    }
    int rv0 = rec[(size_t)bAs[lo0] * RECMAX + (e0 - pfx[lo0])];
    int rv1 = (e1 < T) ? rec[(size_t)bAs[lo1] * RECMAX + (e1 - pfx[lo1])] : 0;

    {
      int q = rv0 >> 13, key = rv0 & 8191;
      int pos = atomicAdd(&lc[q & 127], 1);
      if (pos < CAP) cidx[((size_t)h * 512 + q) * CAP + pos] = key;
    }
    if (e1 < T) {
      int q = rv1 >> 13, key = rv1 & 8191;
      int pos = atomicAdd(&lc[q & 127], 1);
      if (pos < CAP) cidx[((size_t)h * 512 + q) * CAP + pos] = key;
    }
  }
  __syncthreads();
  if (t < 128) cnt[h * 512 + mq * 128 + t] = lc[t];
}

// ---------------------------------------------------------------------------
// Candidate-parallel exact re-score + top-16 membership (double precision).
// ---------------------------------------------------------------------------
__global__ __launch_bounds__(256) void select_topk(const int* __restrict__ cnt,
                                                   const int* __restrict__ cidx,
                                                   const float* __restrict__ qkv,
                                                   const float* __restrict__ kcache,
                                                   const double* __restrict__ kninv,
                                                   int* __restrict__ sel_idx,
                                                   float* __restrict__ sel_score) {
  int w = threadIdx.x >> 6, lane = threadIdx.x & 63;
  int rowid = blockIdx.x * 4 + w;
  int h = rowid >> 9, s = rowid & 511;
  const float* qp = qkv + (size_t)s * (3 * HID) + h * DIM;

  f32x2 qv2 = *(const f32x2*)(qp + lane * 2);
  double qs = (double)qv2[0] * qv2[0] + (double)qv2[1] * qv2[1];
#pragma unroll
  for (int off = 32; off; off >>= 1) qs += __shfl_xor(qs, off);
  double thr = 0.25 * sqrt(qs);

  int n = min(cnt[rowid], CAP);
  int idx = 0x7fffffff;
  double r = -1e300, d = 0.0;
  if (lane < n) {
    idx = cidx[rowid * CAP + lane];
    const float* kp = kcache + ((size_t)(h * SCACHE + idx)) * DIM;
    double d0 = 0.0, d1 = 0.0;
#pragma unroll
    for (int j = 0; j < DIM; j += 8) {
      f32x4 ka = *(const f32x4*)(kp + j);
      f32x4 kb = *(const f32x4*)(kp + j + 4);
      f32x4 qa = *(const f32x4*)(qp + j);
      f32x4 qb = *(const f32x4*)(qp + j + 4);
      d0 = fma((double)qa[0], (double)ka[0], d0);
      d1 = fma((double)qa[1], (double)ka[1], d1);
      d0 = fma((double)qa[2], (double)ka[2], d0);
      d1 = fma((double)qa[3], (double)ka[3], d1);
      d0 = fma((double)qb[0], (double)kb[0], d0);
      d1 = fma((double)qb[1], (double)kb[1], d1);
      d0 = fma((double)qb[2], (double)kb[2], d0);
      d1 = fma((double)qb[3], (double)kb[3], d1);
    }
    d = d0 + d1;
    r = d * kninv[h * SCACHE + idx];
  }

  int rank = 0;
  for (int j = 0; j < n; ++j) {
    double rj = __shfl(r, j);
    int ij = __shfl(idx, j);
    if (rj > r || (rj == r && ij < idx)) ++rank;
  }
  bool sel = (lane < n) && (rank < 16) && (r > thr);
  unsigned long long m = __ballot(sel);
  int nsel = __popcll(m);
  if (sel) {
    int pos = __popcll(m & ((1ull << lane) - 1));
    sel_idx[rowid * 16 + pos] = idx;
    sel_score[rowid * 16 + pos] = (float)(d * (double)SCALE);
  }
  if (lane >= nsel && lane < 16) {
    sel_idx[rowid * 16 + lane] = 0;
    sel_score[rowid * 16 + lane] = NEG_INF;
  }
}

// ---------------------------------------------------------------------------
// Flash-style local attention, stage 1.
// ---------------------------------------------------------------------------
__global__ __launch_bounds__(256) void attn_part(const float* __restrict__ qkv,
                                                 const _Float16* __restrict__ q16,
                                                 const _Float16* __restrict__ k16,
                                                 const float* __restrict__ bias,
                                                 float* __restrict__ part_m,
                                                 float* __restrict__ part_l,
                                                 float* __restrict__ part_o) {
  __shared__ __align__(16) _Float16 Vs[128][136];  // V^T: [dim][key]
  __shared__ __align__(16) _Float16 Ps[16][136];   // P:   [q][key]
  __shared__ float mred[16][4], lred[16][4];

  int pb = blockIdx.x;
  int tt = pb % 80, h = pb / 80;
  int qb, cb;
  if (tt < 8)       { qb = tt;                cb = 0; }
  else if (tt < 24) { int u = tt - 8;  qb = 8 + (u >> 1); cb = u & 1; }
  else if (tt < 48) { int u = tt - 24; int q3 = u / 3; qb = 16 + q3; cb = u - q3 * 3; }
  else              { int u = tt - 48; qb = 24 + (u >> 2); cb = u & 3; }
  int q0 = qb * 16, kc0 = cb * 128;

  int t = threadIdx.x, lane = t & 63, w = t >> 6;
  int quad = lane >> 4, col = lane & 15;

  const float* vbase = qkv + 2 * HID + h * DIM;
#pragma unroll
  for (int i = 0; i < 16; ++i) {
    int idx = t + 256 * i;
    int key = idx & 127, dg = idx >> 7;
    f32x4 vv = *(const f32x4*)(vbase + (size_t)(kc0 + key) * (3 * HID) + dg * 4);
#pragma unroll
    for (int e = 0; e < 4; ++e) Vs[dg * 4 + e][key] = (_Float16)vv[e];
  }

  const _Float16* qbp = q16 + ((size_t)(h * SEQ + q0)) * DIM;
  half8 af[4];
#pragma unroll
  for (int ks = 0; ks < 4; ++ks)
    af[ks] = *(const half8*)(qbp + (size_t)col * DIM + ks * 32 + quad * 8);

  f32x4 acc[2] = {};
#pragma unroll
  for (int jn = 0; jn < 2; ++jn) {
    const _Float16* kp = k16 + ((size_t)(h * SEQ + kc0 + w * 32 + jn * 16 + col)) * DIM;
#pragma unroll
    for (int ks = 0; ks < 4; ++ks) {
      half8 bf = *(const half8*)(kp + ks * 32 + quad * 8);
      acc[jn] = __builtin_amdgcn_mfma_f32_16x16x32_f16(af[ks], bf, acc[jn], 0, 0, 0);
    }
  }
  float s[2][4];
#pragma unroll
  for (int jn = 0; jn < 2; ++jn) {
    int keyg = kc0 + w * 32 + jn * 16 + col;
#pragma unroll
    for (int r = 0; r < 4; ++r) {
      int qrow = q0 + quad * 4 + r;
      float sv = NEG_INF;
      if (keyg <= qrow)
        sv = acc[jn][r] * SCALE + bias[((size_t)h * SEQ + qrow) * SEQ + keyg];
      s[jn][r] = sv;
    }
  }

  float mw[4];
#pragma unroll
  for (int r = 0; r < 4; ++r) {
    float m = fmaxf(s[0][r], s[1][r]);
#pragma unroll
    for (int off = 1; off < 16; off <<= 1) m = fmaxf(m, __shfl_xor(m, off));
    mw[r] = m;
  }
  if (col == 0)
#pragma unroll
    for (int r = 0; r < 4; ++r) mred[quad * 4 + r][w] = mw[r];
  __syncthreads();

  float M[4];
#pragma unroll
  for (int r = 0; r < 4; ++r) {
    int row = quad * 4 + r;
    float m = fmaxf(fmaxf(mred[row][0], mred[row][1]),
                    fmaxf(mred[row][2], mred[row][3]));
    M[r] = m;
    float p0 = __expf(s[0][r] - m);
    float p1 = __expf(s[1][r] - m);
    Ps[row][w * 32 + col] = (_Float16)p0;
    Ps[row][w * 32 + 16 + col] = (_Float16)p1;
    float l = p0 + p1;
#pragma unroll
    for (int off = 1; off < 16; off <<= 1) l += __shfl_xor(l, off);
    if (col == 0) lred[row][w] = l;
  }
  if (w == 0 && col == 0)
#pragma unroll
    for (int r = 0; r < 4; ++r) part_m[pb * 16 + quad * 4 + r] = M[r];
  __syncthreads();

  f32x4 o[2] = {};
#pragma unroll
  for (int jn = 0; jn < 2; ++jn) {
#pragma unroll
    for (int ks = 0; ks < 4; ++ks) {
      half8 a = *(const half8*)&Ps[col][ks * 32 + quad * 8];
      half8 bv = *(const half8*)&Vs[w * 32 + jn * 16 + col][ks * 32 + quad * 8];
      o[jn] = __builtin_amdgcn_mfma_f32_16x16x32_f16(a, bv, o[jn], 0, 0, 0);
    }
  }
#pragma unroll
  for (int jn = 0; jn < 2; ++jn)
#pragma unroll
    for (int r = 0; r < 4; ++r)
      part_o[((size_t)pb * 16 + quad * 4 + r) * 128 + w * 32 + jn * 16 + col] = o[jn][r];
  if (t < 16)
    part_l[pb * 16 + t] = lred[t][0] + lred[t][1] + lred[t][2] + lred[t][3];
}

// ---------------------------------------------------------------------------
// Flash merge: wave per (h,q) row.
// ---------------------------------------------------------------------------
__global__ __launch_bounds__(256) void attn_merge(const float* __restrict__ part_m,
                                                  const float* __restrict__ part_l,
                                                  const float* __restrict__ part_o,
                                                  const int* __restrict__ sel_idx,
                                                  const float* __restrict__ sel_score,
                                                  const float* __restrict__ vcache,
                                                  float* __restrict__ ctx) {
  int w = threadIdx.x >> 6, lane = threadIdx.x & 63;
  int row = blockIdx.x * 4 + w;
  int h = row >> 9, q = row & 511;
  int qb = q >> 4, r = q & 15;
  int base = (qb < 8) ? qb
           : (qb < 16) ? 8 + 2 * (qb - 8)
           : (qb < 24) ? 24 + 3 * (qb - 16)
                       : 48 + 4 * (qb - 24);
  int ncb = (qb >> 3) + 1;
  int pb0 = h * 80 + base;

  float scv[16], mc = NEG_INF;
#pragma unroll
  for (int j = 0; j < 16; ++j) {
    scv[j] = sel_score[row * 16 + j];
    mc = fmaxf(mc, scv[j]);
  }
  float mi[4];
  float M = mc;
  for (int i = 0; i < ncb; ++i) {
    mi[i] = part_m[(pb0 + i) * 16 + r];
    M = fmaxf(M, mi[i]);
  }
  f32x2 O = {0.f, 0.f};
  float L = 0.f;
  for (int i = 0; i < ncb; ++i) {
    float sc = __expf(mi[i] - M);
    f32x2 ov = *(const f32x2*)(part_o + ((size_t)(pb0 + i) * 16 + r) * 128 + lane * 2);
    O += ov * sc;
    L += part_l[(pb0 + i) * 16 + r] * sc;
  }
#pragma unroll
  for (int j = 0; j < 16; ++j) {
    if (scv[j] > NEG_INF) {
      float wv = __expf(scv[j] - M);
      int idx = sel_idx[row * 16 + j];
      f32x2 v = *(const f32x2*)(vcache + ((size_t)(h * SCACHE + idx)) * DIM + lane * 2);
      O += v * wv;
      L += wv;
    }
  }
  f32x2 res = O * (1.f / L);
  *(f32x2*)(ctx + (size_t)q * HID + h * DIM + lane * 2) = res;
}

// ---------------------------------------------------------------------------
extern "C" void kernel_launch(void* const* d_in, const int* in_sizes, int n_in,
                              void* d_out, int out_size, void* d_ws, size_t ws_size,
                              hipStream_t stream) {
  const float* hidden = (const float*)d_in[0];
  const float* Wqkv   = (const float*)d_in[1];
  const float* Wout   = (const float*)d_in[2];
  const float* kcache = (const float*)d_in[3];
  const float* vcache = (const float*)d_in[4];
  const float* bias   = (const float*)d_in[5];

  char* ws = (char*)d_ws;
  size_t off = 0;
  float*    qkv   = (float*)(ws + off);    off += (size_t)SEQ * 3 * HID * 4;
  _Float16* q16   = (_Float16*)(ws + off); off += (size_t)NHEAD * SEQ * DIM * 2;
  _Float16* k16   = (_Float16*)(ws + off); off += (size_t)NHEAD * SEQ * DIM * 2;
  _Float16* qn16  = (_Float16*)(ws + off); off += (size_t)NHEAD * SEQ * DIM * 2;
  _Float16* kn16  = (_Float16*)(ws + off); off += (size_t)NHEAD * SCACHE * DIM * 2;
  double*   kninv = (double*)(ws + off);   off += (size_t)NHEAD * SCACHE * 8;
  int*      ccnt  = (int*)(ws + off);      off += (size_t)NHEAD * SEQ * 4;
  int*      cidx  = (int*)(ws + off);      off += (size_t)NHEAD * SEQ * CAP * 4;
  int*      selidx  = (int*)(ws + off);    off += (size_t)NHEAD * SEQ * 16 * 4;
  float*    selsc   = (float*)(ws + off);  off += (size_t)NHEAD * SEQ * 16 * 4;
  float*    ctx   = (float*)(ws + off);    off += (size_t)SEQ * HID * 4;
  float*    pm    = (float*)(ws + off);    off += (size_t)1280 * 16 * 4;
  float*    pl    = (float*)(ws + off);    off += (size_t)1280 * 16 * 4;
  float*    po    = (float*)(ws + off);    off += (size_t)1280 * 16 * 128 * 4;
  // po region (10.5 MB) is dead until attn_part: sim_cand's record slabs
  // (8 MB + 16 KB) alias it. Prior-iteration po dirt is many dispatches
  // stale (evicted) — unlike gpart, which R2 showed costs a writeback storm.
  int*      rec    = (int*)po;
  int*      reccnt = rec + (size_t)4096 * RECMAX;
  // 32 MB union region, three disjoint lifetimes on the serial stream:
  //  (1) kv split-K partials    (kv gemm -> kv reduce)
  //  (2) q hi/lo f16 buffers    (split_hilo -> gemm_q_hi)   [20 MB]
  //  (3) out-proj partials      (out gemm -> out reduce)
  float*    gpart = (float*)(ws + off);
  _Float16* Ahg = (_Float16*)gpart;                       // 512*2048 f16 = 2 MB
  _Float16* Alg = Ahg + (size_t)SEQ * HID;
  _Float16* Bhg = Alg + (size_t)SEQ * HID;                // 2048*2048 f16 = 8 MB
  _Float16* Blg = Bhg + (size_t)HID * HID;

  cache_norm<<<dim3(NHEAD * SCACHE / 4), dim3(256), 0, stream>>>(kcache, kn16, kninv);
  // k/v thirds: split-K=4, 512 blocks; reduce into qkv cols 2048+ (stride 6144)
  gemm_xwT<<<dim3(4 * 32 * 4), dim3(256), 0, stream>>>(hidden, Wqkv + (size_t)2048 * 2048,
                                                       gpart, 2048, 32, 4);
  reduce_k<<<dim3(SEQ * 4096 / 1024), dim3(256), 0, stream>>>(gpart, qkv + 2048, 4, 4096,
                                                              3 * HID);
  // q third: pre-split hi/lo, then bit-identical 3-term chain, 1024 blocks
  split_hilo<<<dim3(SEQ * HID / 1024), dim3(256), 0, stream>>>(hidden, Ahg, Alg);
  split_hilo<<<dim3(HID * HID / 1024), dim3(256), 0, stream>>>(Wqkv, Bhg, Blg);
  gemm_q_hi<<<dim3(1024), dim3(256), 0, stream>>>(Ahg, Alg, Bhg, Blg, qkv);
  prep_local<<<dim3(NHEAD * SEQ / 4), dim3(256), 0, stream>>>(qkv, q16, k16, qn16);
  sim_cand<<<dim3(4096), dim3(256), 0, stream>>>(qn16, kn16, rec, reccnt);
  cand_merge<<<dim3(64), dim3(256), 0, stream>>>(rec, reccnt, ccnt, cidx);
  select_topk<<<dim3(NHEAD * SEQ / 4), dim3(256), 0, stream>>>(ccnt, cidx, qkv, kcache,
                                                               kninv, selidx, selsc);
  attn_part<<<dim3(16 * 80), dim3(256), 0, stream>>>(qkv, q16, k16, bias, pm, pl, po);
  attn_merge<<<dim3(NHEAD * SEQ / 4), dim3(256), 0, stream>>>(pm, pl, po, selidx, selsc,
                                                              vcache, ctx);
  // out-proj: split-K=8, 512 blocks; reduce into d_out
  gemm_xwT<<<dim3(4 * 16 * 8), dim3(256), 0, stream>>>(ctx, Wout, gpart, 2048, 16, 8);
  reduce_k<<<dim3(SEQ * 2048 / 1024), dim3(256), 0, stream>>>(gpart, (float*)d_out, 8, 2048,
                                                              2048);
}

// Round 6
// 412.885 us; speedup vs baseline: 1.1350x; 1.0153x over previous
//
#include <hip/hip_runtime.h>

typedef _Float16 half8 __attribute__((ext_vector_type(8)));
typedef _Float16 half4 __attribute__((ext_vector_type(4)));
typedef _Float16 half2t __attribute__((ext_vector_type(2)));
typedef float f32x4 __attribute__((ext_vector_type(4)));
typedef float f32x2 __attribute__((ext_vector_type(2)));

#define NHEAD 16
#define SEQ 512
#define DIM 128
#define HID 2048
#define SCACHE 8192
#define CAP 64
#define SCALE 0.08838834764831845f   // 1/sqrt(128)
#define NEG_INF (-__builtin_inff())
#define RECMAX 1024                  // per-block slab (mean hits ~160, ~26 sigma)

// ---------------------------------------------------------------------------
// Split-K tile GEMM: Cpart[kblk] = A[M,K] @ B[N,K]^T slice (f16 MFMA).
// 128x128 tiles, BK=64. Smooth outputs only (k/v, out-proj) — q must not.
// ---------------------------------------------------------------------------
__global__ __launch_bounds__(256) void gemm_xwT(const float* __restrict__ A,
                                                const float* __restrict__ B,
                                                float* __restrict__ Cpart,
                                                int K, int gridN, int kslices) {
  __shared__ __align__(16) _Float16 As[128][84];
  __shared__ __align__(16) _Float16 Bs[128][84];
  int b = blockIdx.x;
  int kblk = b % kslices;
  int nm = b / kslices;
  int nblk = nm % gridN, mblk = nm / gridN;
  int N = gridN * 128;
  int kchunk = K / kslices;
  int t = threadIdx.x;
  int lane = t & 63, wid = t >> 6;
  int wm = (wid >> 1) * 64, wn = (wid & 1) * 64;
  f32x4 acc[4][4] = {};
  const float* Ab = A + (size_t)mblk * 128 * K;
  const float* Bb = B + (size_t)nblk * 128 * K;
  int rowS = t >> 4, c4 = (t & 15) * 4;

  for (int k0 = kblk * kchunk; k0 < kblk * kchunk + kchunk; k0 += 64) {
#pragma unroll
    for (int i = 0; i < 8; ++i) {
      int row = rowS + 16 * i;
      float4 av = *(const float4*)(Ab + (size_t)row * K + k0 + c4);
      float4 bv = *(const float4*)(Bb + (size_t)row * K + k0 + c4);
      half4 ah = {(_Float16)av.x, (_Float16)av.y, (_Float16)av.z, (_Float16)av.w};
      half4 bh = {(_Float16)bv.x, (_Float16)bv.y, (_Float16)bv.z, (_Float16)bv.w};
      *(half4*)&As[row][c4] = ah;
      *(half4*)&Bs[row][c4] = bh;
    }
    __syncthreads();
#pragma unroll
    for (int ks = 0; ks < 2; ++ks) {
      int ko = ks * 32 + (lane >> 4) * 8;
      int rr = lane & 15;
      half8 af[4], bf[4];
#pragma unroll
      for (int i = 0; i < 4; ++i) af[i] = *(const half8*)&As[wm + i * 16 + rr][ko];
#pragma unroll
      for (int j = 0; j < 4; ++j) bf[j] = *(const half8*)&Bs[wn + j * 16 + rr][ko];
#pragma unroll
      for (int i = 0; i < 4; ++i)
#pragma unroll
        for (int j = 0; j < 4; ++j)
          acc[i][j] = __builtin_amdgcn_mfma_f32_16x16x32_f16(af[i], bf[j], acc[i][j], 0, 0, 0);
    }
    __syncthreads();
  }
  float* Cp = Cpart + (size_t)kblk * ((size_t)gridN * 128) * 512;
  int cR = (lane >> 4) * 4, cC = lane & 15;
#pragma unroll
  for (int i = 0; i < 4; ++i)
#pragma unroll
    for (int j = 0; j < 4; ++j) {
      int row = mblk * 128 + wm + i * 16 + cR;
      int col = nblk * 128 + wn + j * 16 + cC;
#pragma unroll
      for (int r = 0; r < 4; ++r)
        Cp[(size_t)(row + r) * N + col] = acc[i][j][r];
    }
}

// Deterministic split-K reduce.
__global__ __launch_bounds__(256) void reduce_k(const float* __restrict__ part,
                                                float* __restrict__ dst,
                                                int kslices, int ncol, int dstride) {
  size_t e = ((size_t)blockIdx.x * 256 + threadIdx.x) * 4;
  size_t slice = (size_t)512 * ncol;
  f32x4 s = *(const f32x4*)(part + e);
  for (int p = 1; p < kslices; ++p)
    s += *(const f32x4*)(part + (size_t)p * slice + e);
  size_t row = e / ncol;
  int col = (int)(e % ncol);
  *(f32x4*)(dst + row * dstride + col) = s;
}

// ---------------------------------------------------------------------------
// Streaming fp32 -> (f16 hi, f16 lo) split. Per-element arithmetic IDENTICAL
// to the former in-GEMM conversion (hi=(f16)x, lo=(f16)(x-(float)hi)) —
// q's bits depend on these exact values.
// ---------------------------------------------------------------------------
__global__ __launch_bounds__(256) void split_hilo(const float* __restrict__ src,
                                                  _Float16* __restrict__ hi,
                                                  _Float16* __restrict__ lo) {
  size_t e = ((size_t)blockIdx.x * 256 + threadIdx.x) * 4;
  f32x4 v = *(const f32x4*)(src + e);
  half4 h = {(_Float16)v[0], (_Float16)v[1], (_Float16)v[2], (_Float16)v[3]};
  half4 l = {(_Float16)(v[0] - (float)h[0]), (_Float16)(v[1] - (float)h[1]),
             (_Float16)(v[2] - (float)h[2]), (_Float16)(v[3] - (float)h[3])};
  *(half4*)(hi + e) = h;
  *(half4*)(lo + e) = l;
}

// ---------------------------------------------------------------------------
// q-third at fp32 accuracy via 3-term f16 split MFMA on PRE-SPLIT inputs.
// BIT-IDENTICAL chain per output (K 0..2048 step 32, order lo*hi, hi*lo,
// hi*hi, acc=0). 32x32 tiles -> 1024 blocks (4/CU, 16 waves/CU).
// Writes into qkv cols 0..2047 (stride 6144).
// ---------------------------------------------------------------------------
__global__ __launch_bounds__(256) void gemm_q_hi(const _Float16* __restrict__ Ahg,
                                                 const _Float16* __restrict__ Alg,
                                                 const _Float16* __restrict__ Bhg,
                                                 const _Float16* __restrict__ Blg,
                                                 float* __restrict__ C) {
  __shared__ __align__(16) _Float16 Ahs[32][72], Als[32][72];
  __shared__ __align__(16) _Float16 Bhs[32][72], Bls[32][72];
  int b = blockIdx.x;
  int nblk = b & 63, mblk = b >> 6;   // 64 n-tiles x 16 m-tiles
  int t = threadIdx.x, lane = t & 63, w = t >> 6;
  int wm = (w >> 1) * 16, wn = (w & 1) * 16;
  int quad = lane >> 4, rr = lane & 15;
  f32x4 acc = {};
  const _Float16* Ab0 = Ahg + (size_t)(mblk * 32) * 2048;
  const _Float16* Ab1 = Alg + (size_t)(mblk * 32) * 2048;
  const _Float16* Bb0 = Bhg + (size_t)(nblk * 32) * 2048;
  const _Float16* Bb1 = Blg + (size_t)(nblk * 32) * 2048;
  int srow = t >> 3, sc = (t & 7) * 8;

  for (int k0 = 0; k0 < 2048; k0 += 64) {
    size_t goff = (size_t)srow * 2048 + k0 + sc;
    *(uint4*)&Ahs[srow][sc] = *(const uint4*)(Ab0 + goff);
    *(uint4*)&Als[srow][sc] = *(const uint4*)(Ab1 + goff);
    *(uint4*)&Bhs[srow][sc] = *(const uint4*)(Bb0 + goff);
    *(uint4*)&Bls[srow][sc] = *(const uint4*)(Bb1 + goff);
    __syncthreads();
#pragma unroll
    for (int ks = 0; ks < 2; ++ks) {
      int ko = ks * 32 + quad * 8;
      half8 afh = *(const half8*)&Ahs[wm + rr][ko];
      half8 afl = *(const half8*)&Als[wm + rr][ko];
      half8 bfh = *(const half8*)&Bhs[wn + rr][ko];
      half8 bfl = *(const half8*)&Bls[wn + rr][ko];
      acc = __builtin_amdgcn_mfma_f32_16x16x32_f16(afl, bfh, acc, 0, 0, 0);
      acc = __builtin_amdgcn_mfma_f32_16x16x32_f16(afh, bfl, acc, 0, 0, 0);
      acc = __builtin_amdgcn_mfma_f32_16x16x32_f16(afh, bfh, acc, 0, 0, 0);
    }
    __syncthreads();
  }
  int row = mblk * 32 + wm + quad * 4;
  int col = nblk * 32 + wn + rr;
#pragma unroll
  for (int r = 0; r < 4; ++r)
    C[(size_t)(row + r) * (3 * HID) + col] = acc[r];
}

// ---------------------------------------------------------------------------
// k_cache: f16 normalized copy (filter) + double 1/||k|| (exact re-scoring).
// ---------------------------------------------------------------------------
__global__ __launch_bounds__(256) void cache_norm(const float* __restrict__ kc,
                                                  _Float16* __restrict__ kn16,
                                                  double* __restrict__ kninv) {
  int w = threadIdx.x >> 6, lane = threadIdx.x & 63;
  int row = blockIdx.x * 4 + w;
  f32x2 v = *(const f32x2*)(kc + (size_t)row * DIM + lane * 2);
  double s = (double)v[0] * v[0] + (double)v[1] * v[1];
#pragma unroll
  for (int off = 32; off; off >>= 1) s += __shfl_xor(s, off);
  float inv = rsqrtf((float)s);
  half2t o = {(_Float16)(v[0] * inv), (_Float16)(v[1] * inv)};
  *(half2t*)(kn16 + (size_t)row * DIM + lane * 2) = o;
  if (lane == 0) kninv[row] = 1.0 / sqrt(s);
}

// ---------------------------------------------------------------------------
// From qkv: per-head f16 q, k_local, normalized q. Wave per (h,s).
// ---------------------------------------------------------------------------
__global__ __launch_bounds__(256) void prep_local(const float* __restrict__ qkv,
                                                  _Float16* __restrict__ q16,
                                                  _Float16* __restrict__ k16,
                                                  _Float16* __restrict__ qn16) {
  int w = threadIdx.x >> 6, lane = threadIdx.x & 63;
  int rid = blockIdx.x * 4 + w;
  int h = rid >> 9, s = rid & 511;
  const float* qp = qkv + (size_t)s * (3 * HID) + h * DIM + lane * 2;
  f32x2 q = *(const f32x2*)qp;
  f32x2 k = *(const f32x2*)(qp + HID);
  float ss = q[0] * q[0] + q[1] * q[1];
#pragma unroll
  for (int off = 32; off; off >>= 1) ss += __shfl_xor(ss, off);
  float inv = rsqrtf(ss);
  half2t qh = {(_Float16)q[0], (_Float16)q[1]};
  half2t kh = {(_Float16)k[0], (_Float16)k[1]};
  half2t qnh = {(_Float16)(q[0] * inv), (_Float16)(q[1] * inv)};
  *(half2t*)(q16 + (size_t)rid * DIM + lane * 2) = qh;
  *(half2t*)(k16 + (size_t)rid * DIM + lane * 2) = kh;
  *(half2t*)(qn16 + (size_t)rid * DIM + lane * 2) = qnh;
}

// ---------------------------------------------------------------------------
// Candidate filter: sim = Qn @ Kn^T, f16 MFMA, threshold 0.249 (margin 1e-3).
// R5 post-mortem: one-shot 128x128 blocks had NO intra-block pipelining —
// every tile paid full A-restage + barrier + B-load latency; MFMA/LDS/L2/
// scan each ~8us but fully serialized = 56us.
// R6: block = (h, mq, 4 key-tiles). A staged to LDS ONCE (one barrier per
// block, amortized 4x); loop over 4 B-tiles with REGISTER PREFETCH: tile
// tt+1's 8 independent 16B loads issue before tile tt's 64 MFMAs -> latency
// hides under compute (no barriers in loop). Scan is BRANCHLESS: 64-bit hit
// mask (cmp+or), then ctz pop-loop touching only real hits (~0.16/thread/
// tile); record = indices only, no dynamic acc access.
// Same MFMA shape + ks order + operand values -> bit-identical sims.
// XCD map: 4 mq-siblings sharing B land on one XCD.
// ---------------------------------------------------------------------------
__global__ __launch_bounds__(256) void sim_cand(const _Float16* __restrict__ qn16,
                                                const _Float16* __restrict__ kn16,
                                                int* __restrict__ rec,
                                                int* __restrict__ reccnt) {
  __shared__ __align__(16) _Float16 As[128 * 128];  // 32 KB, swizzled chunks
  __shared__ int ls_buf[RECMAX];
  __shared__ int ls_cnt;
  int b = blockIdx.x;                 // 1024 blocks
  int xcd = b & 7, slot = b >> 3;
  int mq = slot & 3;                  // q-quarter within head
  int p = (slot >> 2) * 8 + xcd;      // 0..255 = h*16 + g
  int h = p >> 4, g = p & 15;         // g = group of 4 key-tiles
  int t = threadIdx.x, lane = t & 63, w = t >> 6;
  int quad = lane >> 4, rr = lane & 15;
  if (t == 0) ls_cnt = 0;

  // Per-lane B base: row (g*512 + w*32 + rr), col (quad*8). Tile tt adds
  // tt*128 rows; jn adds 16 rows; ks adds 32 cols.
  const _Float16* kbase = kn16 + (size_t)h * SCACHE * DIM
                        + (size_t)(g * 512 + w * 32 + rr) * DIM + quad * 8;
  auto loadB = [&](half8 (&dst)[2][4], int tt) {
#pragma unroll
    for (int jn = 0; jn < 2; ++jn)
#pragma unroll
      for (int ks = 0; ks < 4; ++ks)
        dst[jn][ks] = *(const half8*)(kbase + (size_t)(tt * 128 + jn * 16) * DIM + ks * 32);
  };

  half8 bf[2][4], bn[2][4];
  loadB(bf, 0);   // tile-0 B loads issue first; latency hides under A-stage

  // Stage A-tile (128 q-rows x 128 K) once: 8 coalesced 16B loads/thread,
  // ds_write at chunk (c ^ (row&7)) — read side undoes the XOR.
  {
    const _Float16* qA = qn16 + ((size_t)(h * SEQ + mq * 128)) * DIM;
    uint4 sreg[8];
#pragma unroll
    for (int i = 0; i < 8; ++i) {
      int f = t + 256 * i;
      sreg[i] = *(const uint4*)(qA + (size_t)(f >> 4) * DIM + (f & 15) * 8);
    }
#pragma unroll
    for (int i = 0; i < 8; ++i) {
      int f = t + 256 * i;
      int row = f >> 4, c = f & 15;
      *(uint4*)&As[row * DIM + ((c ^ (row & 7)) * 8)] = sreg[i];
    }
  }
  __syncthreads();

#pragma unroll
  for (int tt = 0; tt < 4; ++tt) {
    if (tt < 3) loadB(bn, tt + 1);    // prefetch next tile (independent loads)

    f32x4 acc[8][2] = {};
#pragma unroll
    for (int i = 0; i < 8; ++i) {
      int R = i * 16 + rr;
      half8 af[4];
#pragma unroll
      for (int ks = 0; ks < 4; ++ks)
        af[ks] = *(const half8*)&As[R * DIM + (((ks * 4 + quad) ^ (rr & 7)) * 8)];
#pragma unroll
      for (int jn = 0; jn < 2; ++jn)
#pragma unroll
        for (int ks = 0; ks < 4; ++ks)
          acc[i][jn] = __builtin_amdgcn_mfma_f32_16x16x32_f16(af[ks], bf[jn][ks], acc[i][jn], 0, 0, 0);
    }

    // Branchless hit-mask, then pop only actual hits.
    unsigned long long hm = 0ull;
#pragma unroll
    for (int i = 0; i < 8; ++i)
#pragma unroll
      for (int jn = 0; jn < 2; ++jn)
#pragma unroll
        for (int r = 0; r < 4; ++r)
          hm |= (unsigned long long)(acc[i][jn][r] > 0.249f) << (i * 8 + jn * 4 + r);
    int key_base = (g * 4 + tt) * 128 + w * 32 + rr;
    while (hm) {
      int bit = __builtin_ctzll(hm);
      hm &= hm - 1;
      int i = bit >> 3, jn = (bit >> 2) & 1, r = bit & 3;
      int q = mq * 128 + i * 16 + (quad << 2) + r;     // head-local q row
      int pq = atomicAdd(&ls_cnt, 1);                  // LDS atomic only
      if (pq < RECMAX) ls_buf[pq] = (q << 13) | (key_base + jn * 16);
    }

    if (tt < 3) {
#pragma unroll
      for (int jn = 0; jn < 2; ++jn)
#pragma unroll
        for (int ks = 0; ks < 4; ++ks)
          bf[jn][ks] = bn[jn][ks];
    }
  }
  __syncthreads();
  int total = ls_cnt;
  if (total > RECMAX) total = RECMAX;
  int* rp = rec + (size_t)b * RECMAX;
  for (int e = t; e < total; e += 256) rp[e] = ls_buf[e];  // plain coalesced stores
  if (t == 0) reccnt[b] = total;
}

// ---------------------------------------------------------------------------
// Scatter per-block record slabs into cnt/cidx. 64 blocks, one per (h, mq)
// — record q field encodes mq, so row ownership stays disjoint (LDS counters
// only). Flat cooperative drain: gather the 16 slab counts, prefix-sum in
// LDS, then all 256 threads walk the flat record space with independent
// 2-way-unrolled loads.
// ---------------------------------------------------------------------------
__global__ __launch_bounds__(256) void cand_merge(const int* __restrict__ rec,
                                                  const int* __restrict__ reccnt,
                                                  int* __restrict__ cnt,
                                                  int* __restrict__ cidx) {
  __shared__ int lc[128];
  __shared__ int pfx[17];
  __shared__ int bAs[16];
  int blk = blockIdx.x;              // 0..63
  int h = blk >> 2, mq = blk & 3;
  int t = threadIdx.x;
  if (t < 128) lc[t] = 0;
  if (t < 16) {
    int p = h * 16 + t;                               // h*16 + g
    int bA = (p & 7) + 8 * (((p >> 3) << 2) + mq);    // inverse XCD map
    bAs[t] = bA;
    pfx[t + 1] = reccnt[bA];
  }
  if (t == 0) pfx[0] = 0;
  __syncthreads();
  if (t == 0) {
    int s = 0;
    for (int i = 1; i <= 16; ++i) { s += pfx[i]; pfx[i] = s; }
  }
  __syncthreads();
  int T = pfx[16];

  for (int e0 = t; e0 < T; e0 += 512) {
    int e1 = e0 + 256;
    // two independent binary searches (LDS) + two independent global loads
    int lo0 = 0, hi0 = 16;
#pragma unroll
    for (int it = 0; it < 4; ++it) {
      int mid = (lo0 + hi0) >> 1;
      if (pfx[mid] <= e0) lo0 = mid; else hi0 = mid;
    }
    int lo1 = 0;
    if (e1 < T) {
      int hi1 = 16;
#pragma unroll
      for (int it = 0; it < 4; ++it) {
        int mid = (lo1 + hi1) >> 1;
        if (pfx[mid] <= e1) lo1 = mid; else hi1 = mid;
      }
    }
    int rv0 = rec[(size_t)bAs[lo0] * RECMAX + (e0 - pfx[lo0])];
    int rv1 = (e1 < T) ? rec[(size_t)bAs[lo1] * RECMAX + (e1 - pfx[lo1])] : 0;

    {
      int q = rv0 >> 13, key = rv0 & 8191;
      int pos = atomicAdd(&lc[q & 127], 1);
      if (pos < CAP) cidx[((size_t)h * 512 + q) * CAP + pos] = key;
    }
    if (e1 < T) {
      int q = rv1 >> 13, key = rv1 & 8191;
      int pos = atomicAdd(&lc[q & 127], 1);
      if (pos < CAP) cidx[((size_t)h * 512 + q) * CAP + pos] = key;
    }
  }
  __syncthreads();
  if (t < 128) cnt[h * 512 + mq * 128 + t] = lc[t];
}

// ---------------------------------------------------------------------------
// Candidate-parallel exact re-score + top-16 membership (double precision).
// ---------------------------------------------------------------------------
__global__ __launch_bounds__(256) void select_topk(const int* __restrict__ cnt,
                                                   const int* __restrict__ cidx,
                                                   const float* __restrict__ qkv,
                                                   const float* __restrict__ kcache,
                                                   const double* __restrict__ kninv,
                                                   int* __restrict__ sel_idx,
                                                   float* __restrict__ sel_score) {
  int w = threadIdx.x >> 6, lane = threadIdx.x & 63;
  int rowid = blockIdx.x * 4 + w;
  int h = rowid >> 9, s = rowid & 511;
  const float* qp = qkv + (size_t)s * (3 * HID) + h * DIM;

  f32x2 qv2 = *(const f32x2*)(qp + lane * 2);
  double qs = (double)qv2[0] * qv2[0] + (double)qv2[1] * qv2[1];
#pragma unroll
  for (int off = 32; off; off >>= 1) qs += __shfl_xor(qs, off);
  double thr = 0.25 * sqrt(qs);

  int n = min(cnt[rowid], CAP);
  int idx = 0x7fffffff;
  double r = -1e300, d = 0.0;
  if (lane < n) {
    idx = cidx[rowid * CAP + lane];
    const float* kp = kcache + ((size_t)(h * SCACHE + idx)) * DIM;
    double d0 = 0.0, d1 = 0.0;
#pragma unroll
    for (int j = 0; j < DIM; j += 8) {
      f32x4 ka = *(const f32x4*)(kp + j);
      f32x4 kb = *(const f32x4*)(kp + j + 4);
      f32x4 qa = *(const f32x4*)(qp + j);
      f32x4 qb = *(const f32x4*)(qp + j + 4);
      d0 = fma((double)qa[0], (double)ka[0], d0);
      d1 = fma((double)qa[1], (double)ka[1], d1);
      d0 = fma((double)qa[2], (double)ka[2], d0);
      d1 = fma((double)qa[3], (double)ka[3], d1);
      d0 = fma((double)qb[0], (double)kb[0], d0);
      d1 = fma((double)qb[1], (double)kb[1], d1);
      d0 = fma((double)qb[2], (double)kb[2], d0);
      d1 = fma((double)qb[3], (double)kb[3], d1);
    }
    d = d0 + d1;
    r = d * kninv[h * SCACHE + idx];
  }

  int rank = 0;
  for (int j = 0; j < n; ++j) {
    double rj = __shfl(r, j);
    int ij = __shfl(idx, j);
    if (rj > r || (rj == r && ij < idx)) ++rank;
  }
  bool sel = (lane < n) && (rank < 16) && (r > thr);
  unsigned long long m = __ballot(sel);
  int nsel = __popcll(m);
  if (sel) {
    int pos = __popcll(m & ((1ull << lane) - 1));
    sel_idx[rowid * 16 + pos] = idx;
    sel_score[rowid * 16 + pos] = (float)(d * (double)SCALE);
  }
  if (lane >= nsel && lane < 16) {
    sel_idx[rowid * 16 + lane] = 0;
    sel_score[rowid * 16 + lane] = NEG_INF;
  }
}

// ---------------------------------------------------------------------------
// Flash-style local attention, stage 1.
// ---------------------------------------------------------------------------
__global__ __launch_bounds__(256) void attn_part(const float* __restrict__ qkv,
                                                 const _Float16* __restrict__ q16,
                                                 const _Float16* __restrict__ k16,
                                                 const float* __restrict__ bias,
                                                 float* __restrict__ part_m,
                                                 float* __restrict__ part_l,
                                                 float* __restrict__ part_o) {
  __shared__ __align__(16) _Float16 Vs[128][136];  // V^T: [dim][key]
  __shared__ __align__(16) _Float16 Ps[16][136];   // P:   [q][key]
  __shared__ float mred[16][4], lred[16][4];

  int pb = blockIdx.x;
  int tt = pb % 80, h = pb / 80;
  int qb, cb;
  if (tt < 8)       { qb = tt;                cb = 0; }
  else if (tt < 24) { int u = tt - 8;  qb = 8 + (u >> 1); cb = u & 1; }
  else if (tt < 48) { int u = tt - 24; int q3 = u / 3; qb = 16 + q3; cb = u - q3 * 3; }
  else              { int u = tt - 48; qb = 24 + (u >> 2); cb = u & 3; }
  int q0 = qb * 16, kc0 = cb * 128;

  int t = threadIdx.x, lane = t & 63, w = t >> 6;
  int quad = lane >> 4, col = lane & 15;

  const float* vbase = qkv + 2 * HID + h * DIM;
#pragma unroll
  for (int i = 0; i < 16; ++i) {
    int idx = t + 256 * i;
    int key = idx & 127, dg = idx >> 7;
    f32x4 vv = *(const f32x4*)(vbase + (size_t)(kc0 + key) * (3 * HID) + dg * 4);
#pragma unroll
    for (int e = 0; e < 4; ++e) Vs[dg * 4 + e][key] = (_Float16)vv[e];
  }

  const _Float16* qbp = q16 + ((size_t)(h * SEQ + q0)) * DIM;
  half8 af[4];
#pragma unroll
  for (int ks = 0; ks < 4; ++ks)
    af[ks] = *(const half8*)(qbp + (size_t)col * DIM + ks * 32 + quad * 8);

  f32x4 acc[2] = {};
#pragma unroll
  for (int jn = 0; jn < 2; ++jn) {
    const _Float16* kp = k16 + ((size_t)(h * SEQ + kc0 + w * 32 + jn * 16 + col)) * DIM;
#pragma unroll
    for (int ks = 0; ks < 4; ++ks) {
      half8 bf = *(const half8*)(kp + ks * 32 + quad * 8);
      acc[jn] = __builtin_amdgcn_mfma_f32_16x16x32_f16(af[ks], bf, acc[jn], 0, 0, 0);
    }
  }
  float s[2][4];
#pragma unroll
  for (int jn = 0; jn < 2; ++jn) {
    int keyg = kc0 + w * 32 + jn * 16 + col;
#pragma unroll
    for (int r = 0; r < 4; ++r) {
      int qrow = q0 + quad * 4 + r;
      float sv = NEG_INF;
      if (keyg <= qrow)
        sv = acc[jn][r] * SCALE + bias[((size_t)h * SEQ + qrow) * SEQ + keyg];
      s[jn][r] = sv;
    }
  }

  float mw[4];
#pragma unroll
  for (int r = 0; r < 4; ++r) {
    float m = fmaxf(s[0][r], s[1][r]);
#pragma unroll
    for (int off = 1; off < 16; off <<= 1) m = fmaxf(m, __shfl_xor(m, off));
    mw[r] = m;
  }
  if (col == 0)
#pragma unroll
    for (int r = 0; r < 4; ++r) mred[quad * 4 + r][w] = mw[r];
  __syncthreads();

  float M[4];
#pragma unroll
  for (int r = 0; r < 4; ++r) {
    int row = quad * 4 + r;
    float m = fmaxf(fmaxf(mred[row][0], mred[row][1]),
                    fmaxf(mred[row][2], mred[row][3]));
    M[r] = m;
    float p0 = __expf(s[0][r] - m);
    float p1 = __expf(s[1][r] - m);
    Ps[row][w * 32 + col] = (_Float16)p0;
    Ps[row][w * 32 + 16 + col] = (_Float16)p1;
    float l = p0 + p1;
#pragma unroll
    for (int off = 1; off < 16; off <<= 1) l += __shfl_xor(l, off);
    if (col == 0) lred[row][w] = l;
  }
  if (w == 0 && col == 0)
#pragma unroll
    for (int r = 0; r < 4; ++r) part_m[pb * 16 + quad * 4 + r] = M[r];
  __syncthreads();

  f32x4 o[2] = {};
#pragma unroll
  for (int jn = 0; jn < 2; ++jn) {
#pragma unroll
    for (int ks = 0; ks < 4; ++ks) {
      half8 a = *(const half8*)&Ps[col][ks * 32 + quad * 8];
      half8 bv = *(const half8*)&Vs[w * 32 + jn * 16 + col][ks * 32 + quad * 8];
      o[jn] = __builtin_amdgcn_mfma_f32_16x16x32_f16(a, bv, o[jn], 0, 0, 0);
    }
  }
#pragma unroll
  for (int jn = 0; jn < 2; ++jn)
#pragma unroll
    for (int r = 0; r < 4; ++r)
      part_o[((size_t)pb * 16 + quad * 4 + r) * 128 + w * 32 + jn * 16 + col] = o[jn][r];
  if (t < 16)
    part_l[pb * 16 + t] = lred[t][0] + lred[t][1] + lred[t][2] + lred[t][3];
}

// ---------------------------------------------------------------------------
// Flash merge: wave per (h,q) row.
// ---------------------------------------------------------------------------
__global__ __launch_bounds__(256) void attn_merge(const float* __restrict__ part_m,
                                                  const float* __restrict__ part_l,
                                                  const float* __restrict__ part_o,
                                                  const int* __restrict__ sel_idx,
                                                  const float* __restrict__ sel_score,
                                                  const float* __restrict__ vcache,
                                                  float* __restrict__ ctx) {
  int w = threadIdx.x >> 6, lane = threadIdx.x & 63;
  int row = blockIdx.x * 4 + w;
  int h = row >> 9, q = row & 511;
  int qb = q >> 4, r = q & 15;
  int base = (qb < 8) ? qb
           : (qb < 16) ? 8 + 2 * (qb - 8)
           : (qb < 24) ? 24 + 3 * (qb - 16)
                       : 48 + 4 * (qb - 24);
  int ncb = (qb >> 3) + 1;
  int pb0 = h * 80 + base;

  float scv[16], mc = NEG_INF;
#pragma unroll
  for (int j = 0; j < 16; ++j) {
    scv[j] = sel_score[row * 16 + j];
    mc = fmaxf(mc, scv[j]);
  }
  float mi[4];
  float M = mc;
  for (int i = 0; i < ncb; ++i) {
    mi[i] = part_m[(pb0 + i) * 16 + r];
    M = fmaxf(M, mi[i]);
  }
  f32x2 O = {0.f, 0.f};
  float L = 0.f;
  for (int i = 0; i < ncb; ++i) {
    float sc = __expf(mi[i] - M);
    f32x2 ov = *(const f32x2*)(part_o + ((size_t)(pb0 + i) * 16 + r) * 128 + lane * 2);
    O += ov * sc;
    L += part_l[(pb0 + i) * 16 + r] * sc;
  }
#pragma unroll
  for (int j = 0; j < 16; ++j) {
    if (scv[j] > NEG_INF) {
      float wv = __expf(scv[j] - M);
      int idx = sel_idx[row * 16 + j];
      f32x2 v = *(const f32x2*)(vcache + ((size_t)(h * SCACHE + idx)) * DIM + lane * 2);
      O += v * wv;
      L += wv;
    }
  }
  f32x2 res = O * (1.f / L);
  *(f32x2*)(ctx + (size_t)q * HID + h * DIM + lane * 2) = res;
}

// ---------------------------------------------------------------------------
extern "C" void kernel_launch(void* const* d_in, const int* in_sizes, int n_in,
                              void* d_out, int out_size, void* d_ws, size_t ws_size,
                              hipStream_t stream) {
  const float* hidden = (const float*)d_in[0];
  const float* Wqkv   = (const float*)d_in[1];
  const float* Wout   = (const float*)d_in[2];
  const float* kcache = (const float*)d_in[3];
  const float* vcache = (const float*)d_in[4];
  const float* bias   = (const float*)d_in[5];

  char* ws = (char*)d_ws;
  size_t off = 0;
  float*    qkv   = (float*)(ws + off);    off += (size_t)SEQ * 3 * HID * 4;
  _Float16* q16   = (_Float16*)(ws + off); off += (size_t)NHEAD * SEQ * DIM * 2;
  _Float16* k16   = (_Float16*)(ws + off); off += (size_t)NHEAD * SEQ * DIM * 2;
  _Float16* qn16  = (_Float16*)(ws + off); off += (size_t)NHEAD * SEQ * DIM * 2;
  _Float16* kn16  = (_Float16*)(ws + off); off += (size_t)NHEAD * SCACHE * DIM * 2;
  double*   kninv = (double*)(ws + off);   off += (size_t)NHEAD * SCACHE * 8;
  int*      ccnt  = (int*)(ws + off);      off += (size_t)NHEAD * SEQ * 4;
  int*      cidx  = (int*)(ws + off);      off += (size_t)NHEAD * SEQ * CAP * 4;
  int*      selidx  = (int*)(ws + off);    off += (size_t)NHEAD * SEQ * 16 * 4;
  float*    selsc   = (float*)(ws + off);  off += (size_t)NHEAD * SEQ * 16 * 4;
  float*    ctx   = (float*)(ws + off);    off += (size_t)SEQ * HID * 4;
  float*    pm    = (float*)(ws + off);    off += (size_t)1280 * 16 * 4;
  float*    pl    = (float*)(ws + off);    off += (size_t)1280 * 16 * 4;
  float*    po    = (float*)(ws + off);    off += (size_t)1280 * 16 * 128 * 4;
  // po region (10.5 MB) is dead until attn_part: sim_cand's record slabs
  // (4 MB + 4 KB) alias it. Prior-iteration po dirt is many dispatches
  // stale (evicted) — unlike gpart, which R2 showed costs a writeback storm.
  int*      rec    = (int*)po;
  int*      reccnt = rec + (size_t)1024 * RECMAX;
  // 32 MB union region, three disjoint lifetimes on the serial stream:
  //  (1) kv split-K partials    (kv gemm -> kv reduce)
  //  (2) q hi/lo f16 buffers    (split_hilo -> gemm_q_hi)   [20 MB]
  //  (3) out-proj partials      (out gemm -> out reduce)
  float*    gpart = (float*)(ws + off);
  _Float16* Ahg = (_Float16*)gpart;                       // 512*2048 f16 = 2 MB
  _Float16* Alg = Ahg + (size_t)SEQ * HID;
  _Float16* Bhg = Alg + (size_t)SEQ * HID;                // 2048*2048 f16 = 8 MB
  _Float16* Blg = Bhg + (size_t)HID * HID;

  cache_norm<<<dim3(NHEAD * SCACHE / 4), dim3(256), 0, stream>>>(kcache, kn16, kninv);
  // k/v thirds: split-K=4, 512 blocks; reduce into qkv cols 2048+ (stride 6144)
  gemm_xwT<<<dim3(4 * 32 * 4), dim3(256), 0, stream>>>(hidden, Wqkv + (size_t)2048 * 2048,
                                                       gpart, 2048, 32, 4);
  reduce_k<<<dim3(SEQ * 4096 / 1024), dim3(256), 0, stream>>>(gpart, qkv + 2048, 4, 4096,
                                                              3 * HID);
  // q third: pre-split hi/lo, then bit-identical 3-term chain, 1024 blocks
  split_hilo<<<dim3(SEQ * HID / 1024), dim3(256), 0, stream>>>(hidden, Ahg, Alg);
  split_hilo<<<dim3(HID * HID / 1024), dim3(256), 0, stream>>>(Wqkv, Bhg, Blg);
  gemm_q_hi<<<dim3(1024), dim3(256), 0, stream>>>(Ahg, Alg, Bhg, Blg, qkv);
  prep_local<<<dim3(NHEAD * SEQ / 4), dim3(256), 0, stream>>>(qkv, q16, k16, qn16);
  sim_cand<<<dim3(1024), dim3(256), 0, stream>>>(qn16, kn16, rec, reccnt);
  cand_merge<<<dim3(64), dim3(256), 0, stream>>>(rec, reccnt, ccnt, cidx);
  select_topk<<<dim3(NHEAD * SEQ / 4), dim3(256), 0, stream>>>(ccnt, cidx, qkv, kcache,
                                                               kninv, selidx, selsc);
  attn_part<<<dim3(16 * 80), dim3(256), 0, stream>>>(qkv, q16, k16, bias, pm, pl, po);
  attn_merge<<<dim3(NHEAD * SEQ / 4), dim3(256), 0, stream>>>(pm, pl, po, selidx, selsc,
                                                              vcache, ctx);
  // out-proj: split-K=8, 512 blocks; reduce into d_out
  gemm_xwT<<<dim3(4 * 16 * 8), dim3(256), 0, stream>>>(ctx, Wout, gpart, 2048, 16, 8);
  reduce_k<<<dim3(SEQ * 2048 / 1024), dim3(256), 0, stream>>>(gpart, (float*)d_out, 8, 2048,
                                                              2048);
}